// Round 6
// baseline (7958.681 us; speedup 1.0000x reference)
//
#include <hip/hip_runtime.h>

#define N_TOK 131072
#define KC    1024
#define DIM   256
#define GAP_THR 2.5e-4f

typedef __attribute__((ext_vector_type(8)))  short bf16x8;
typedef __attribute__((ext_vector_type(16))) float f32x16;

__device__ __forceinline__ unsigned short f2bf(float f) {
    unsigned int u = __float_as_uint(f);
    unsigned int r = (u + 0x7fffu + ((u >> 16) & 1u)) >> 16;   // RNE
    return (unsigned short)r;
}

// ================= ws layout (MFMA path) =================
// 0         : z16   (bf16)  67108864 B
// 67108864  : m12   (float2) 8388608 B   [cb][token] (m1,m2)
// 75497472  : idxp  (int)    4194304 B   [cb][token]
// 79691776  : cb16  (bf16)    524288 B
// 80216064  : cnorm (f32)       4096 B
// 80220160  : zzg   (f32)     524288 B
// 80744448  : flag_count (u32)    64 B
// 80744512  : flag_list (int)  524288 B
// 81268800  : loss partials  16384 B
#define WS_NEED 81285184ull

__global__ void vq_zero(unsigned int* p) { if (threadIdx.x == 0) *p = 0u; }

// ---- prep: z -> bf16 + row norms (one wave per row) ----
__global__ void vq_prep_z(const float* __restrict__ z, unsigned short* __restrict__ z16,
                          float* __restrict__ zzg) {
    int row  = blockIdx.x * 4 + (threadIdx.x >> 6);
    int lane = threadIdx.x & 63;
    float4 v = ((const float4*)z)[(size_t)row * 64 + lane];
    ushort4 h;
    h.x = f2bf(v.x); h.y = f2bf(v.y); h.z = f2bf(v.z); h.w = f2bf(v.w);
    ((ushort4*)z16)[(size_t)row * 64 + lane] = h;
    double s = 0.0;
    s = fma((double)v.x, (double)v.x, s);
    s = fma((double)v.y, (double)v.y, s);
    s = fma((double)v.z, (double)v.z, s);
    s = fma((double)v.w, (double)v.w, s);
    #pragma unroll
    for (int off = 32; off > 0; off >>= 1) s += __shfl_xor(s, off);
    if (lane == 0) zzg[row] = (float)s;   // uniform per-row shift: argmin-invariant
}

__global__ void vq_prep_cb(const float* __restrict__ cb, unsigned short* __restrict__ cb16,
                           float* __restrict__ cnorm) {
    int code = blockIdx.x * 4 + (threadIdx.x >> 6);
    int lane = threadIdx.x & 63;
    float4 v = ((const float4*)cb)[(size_t)code * 64 + lane];
    ushort4 h;
    h.x = f2bf(v.x); h.y = f2bf(v.y); h.z = f2bf(v.z); h.w = f2bf(v.w);
    ((ushort4*)cb16)[(size_t)code * 64 + lane] = h;
    double s = 0.0;
    s = fma((double)v.x, (double)v.x, s);
    s = fma((double)v.y, (double)v.y, s);
    s = fma((double)v.z, (double)v.z, s);
    s = fma((double)v.w, (double)v.w, s);
    #pragma unroll
    for (int off = 32; off > 0; off >>= 1) s += __shfl_xor(s, off);
    if (lane == 0) cnorm[code] = (float)s;
}

// ---- MFMA scores: transposed GEMM (rows=codes, cols=tokens) ----
// Block: 256 thr = 4 waves (2 code-half x 2 token-half), tile 128 codes x 128 tokens.
// LDS tiles XOR-swizzled at b128 granularity: u32 unit du ^ ((row&7)<<2).
// Epilogue: per-wave top-2 -> LDS merge of the two code-halves (fixes R5 race).
__global__ __launch_bounds__(256, 4)
void vq_scores_mfma(const unsigned short* __restrict__ z16, const unsigned short* __restrict__ cb16,
                    const float* __restrict__ cnorm, const float* __restrict__ zzg,
                    float2* __restrict__ m12, int* __restrict__ idxp)
{
    __shared__ unsigned int cA[128 * 32];   // 128 codes x 64 dims bf16 (16 KB)
    __shared__ unsigned int zA[128 * 32];   // 128 tokens x 64 dims bf16
    __shared__ float cns[128];

    const int tid = threadIdx.x;
    const int lane = tid & 63;
    const int l31 = lane & 31;
    const int hi = lane >> 5;
    const int wid = tid >> 6;
    const int wcode = wid >> 1;             // 0..1 : code half
    const int wtok = wid & 1;               // 0..1 : token half
    const int cbk = blockIdx.x >> 9;        // code block 0..7
    const int tb = blockIdx.x & 511;        // token block 0..511

    if (tid < 128) cns[tid] = cnorm[cbk * 128 + tid];

    f32x16 acc[2][2];
    #pragma unroll
    for (int a = 0; a < 2; ++a)
        #pragma unroll
        for (int b = 0; b < 2; ++b)
            #pragma unroll
            for (int r = 0; r < 16; ++r) acc[a][b][r] = 0.0f;

    #pragma unroll
    for (int kb = 0; kb < 4; ++kb) {
        if (kb) __syncthreads();
        #pragma unroll
        for (int i = 0; i < 16; ++i) {      // stage codes tile: 128 x 32 u32
            int g = tid + i * 256;
            int c = g >> 5, du = g & 31;
            cA[c * 32 + (du ^ ((c & 7) << 2))] =
                ((const unsigned int*)cb16)[(size_t)(cbk * 128 + c) * 128 + kb * 32 + du];
        }
        #pragma unroll
        for (int i = 0; i < 16; ++i) {      // stage tokens tile
            int g = tid + i * 256;
            int t = g >> 5, du = g & 31;
            zA[t * 32 + (du ^ ((t & 7) << 2))] =
                ((const unsigned int*)z16)[(size_t)(tb * 128 + t) * 128 + kb * 32 + du];
        }
        __syncthreads();

        #pragma unroll
        for (int ks = 0; ks < 4; ++ks) {
            bf16x8 af[2], bf[2];
            #pragma unroll
            for (int f = 0; f < 2; ++f) {
                int c = wcode * 64 + f * 32 + l31;
                af[f] = ((const bf16x8*)cA)[c * 8 + ((ks * 2 + hi) ^ (c & 7))];
                int t = wtok * 64 + f * 32 + l31;
                bf[f] = ((const bf16x8*)zA)[t * 8 + ((ks * 2 + hi) ^ (t & 7))];
            }
            #pragma unroll
            for (int a = 0; a < 2; ++a)
                #pragma unroll
                for (int b = 0; b < 2; ++b)
                    acc[a][b] = __builtin_amdgcn_mfma_f32_32x32x16_bf16(af[a], bf[b], acc[a][b], 0, 0, 0);
        }
    }

    __syncthreads();                        // MFMA reads done -> reuse cA as merge scratch
    float* sm1 = (float*)cA;                // [2][128]
    float* sm2 = sm1 + 256;                 // [2][128]
    int*   sid = (int*)(sm2 + 256);         // [2][128]

    // per token: top-2 + lowest-index over this wave's 64 codes, then hi-half merge.
    // C layout (32x32): col=lane&31 (token), row=(reg&3)+8*(reg>>2)+4*hi (code)
    #pragma unroll
    for (int tf = 0; tf < 2; ++tf) {
        int ltok = wtok * 64 + tf * 32 + l31;
        float zz = zzg[tb * 128 + ltok];
        float m1 = 3.0e38f, m2 = 3.0e38f;
        #pragma unroll
        for (int cf = 0; cf < 2; ++cf)
            #pragma unroll
            for (int r = 0; r < 16; ++r) {
                int cl = wcode * 64 + cf * 32 + (r & 3) + 8 * (r >> 2) + 4 * hi;
                float A = zz + cns[cl];                       // fl(zz+cc)
                float dq = fmaf(acc[cf][tf][r], -2.0f, A);    // == fl(A - fl(2e)), 2e exact
                acc[cf][tf][r] = dq;                          // keep for idx pass
                float hv = fmaxf(m1, dq);
                m1 = fminf(m1, dq);
                m2 = fminf(m2, hv);                           // dup minima -> m2==m1 -> flagged
            }
        int idx = 0x7fffffff;
        #pragma unroll
        for (int cf = 0; cf < 2; ++cf)
            #pragma unroll
            for (int r = 0; r < 16; ++r) {
                int code = cbk * 128 + wcode * 64 + cf * 32 + (r & 3) + 8 * (r >> 2) + 4 * hi;
                idx = min(idx, (acc[cf][tf][r] == m1) ? code : 0x7fffffff);
            }
        // merge lane <-> lane^32 (same token, other code rows within this wave)
        float m1o = __shfl_xor(m1, 32);
        float m2o = __shfl_xor(m2, 32);
        int  idxo = __shfl_xor(idx, 32);
        float nm2 = fminf(fminf(m2, m2o), fmaxf(m1, m1o));
        int nidx = (m1o < m1 || (m1o == m1 && idxo < idx)) ? idxo : idx;
        float nm1 = fminf(m1, m1o);
        if (hi == 0) {
            sm1[wcode * 128 + ltok] = nm1;
            sm2[wcode * 128 + ltok] = nm2;
            sid[wcode * 128 + ltok] = nidx;
        }
    }
    __syncthreads();

    // merge the two code halves (128 threads, one per token) -> single global write
    if (tid < 128) {
        float a1 = sm1[tid],       a2 = sm2[tid];       int ai = sid[tid];
        float b1 = sm1[128 + tid], b2 = sm2[128 + tid]; int bi = sid[128 + tid];
        float m1, m2; int ix;
        if (b1 < a1 || (b1 == a1 && bi < ai)) { m1 = b1; ix = bi; m2 = fminf(b2, a1); }
        else                                   { m1 = a1; ix = ai; m2 = fminf(a2, b1); }
        size_t p = (size_t)cbk * N_TOK + tb * 128 + tid;
        m12[p] = make_float2(m1, m2);
        idxp[p] = ix;
    }
}

// ---- merge 8 code-block partials per token; flag near-ties ----
__global__ void vq_merge(const float2* __restrict__ m12, const int* __restrict__ idxp,
                         float* __restrict__ out_idx, int* __restrict__ flag_list,
                         unsigned int* __restrict__ flag_count)
{
    int t = blockIdx.x * 256 + threadIdx.x;
    float m1 = 3.0e38f, m2 = 3.0e38f; int i1 = 0x7fffffff;
    #pragma unroll
    for (int c = 0; c < 8; ++c) {
        float2 p = m12[(size_t)c * N_TOK + t];
        int ip = idxp[(size_t)c * N_TOK + t];
        if (p.x < m1 || (p.x == m1 && ip < i1)) {
            m2 = fminf(fminf(m1, p.y), m2);
            m1 = p.x; i1 = ip;
        } else {
            m2 = fminf(m2, p.x);
        }
    }
    out_idx[t] = (float)i1;
    if (!(m2 - m1 > GAP_THR)) {          // near-tie or NaN-safety -> exact recheck
        unsigned int p = atomicAdd(flag_count, 1u);
        flag_list[p] = t;
    }
}

// ---- exact f32-chain argmin for flagged rows (np-faithful, same as R2/R4 pass) ----
__global__ void vq_recheck(const float* __restrict__ z, const float* __restrict__ cb,
                           const float* __restrict__ cnorm, const float* __restrict__ zzg,
                           const int* __restrict__ flag_list, const unsigned int* __restrict__ flag_count,
                           float* __restrict__ out_idx)
{
    __shared__ float zrow[DIM];
    __shared__ float sval[256];
    __shared__ int   sidx[256];
    const int tid = threadIdx.x;
    const unsigned int cnt = *flag_count;

    for (unsigned int f = blockIdx.x; f < cnt; f += gridDim.x) {
        const int row = flag_list[f];
        zrow[tid] = z[(size_t)row * DIM + tid];
        __syncthreads();
        const float zz = zzg[row];
        float bm = 3.0e38f; int bidx = 0x7fffffff;
        for (int k = 0; k < 4; ++k) {
            int code = tid + k * 256;                    // ascending per thread
            const float4* c4 = (const float4*)(cb + (size_t)code * DIM);
            float e = 0.0f;
            #pragma unroll 16
            for (int d4 = 0; d4 < 64; ++d4) {            // strict sequential k = 0..255
                float4 cv = c4[d4];
                e = fmaf(zrow[d4 * 4 + 0], cv.x, e);
                e = fmaf(zrow[d4 * 4 + 1], cv.y, e);
                e = fmaf(zrow[d4 * 4 + 2], cv.z, e);
                e = fmaf(zrow[d4 * 4 + 3], cv.w, e);
            }
            float A = zz + cnorm[code];
            float dq = A - 2.0f * e;
            if (dq < bm) { bm = dq; bidx = code; }       // strict < keeps lowest code
        }
        sval[tid] = bm; sidx[tid] = bidx;
        __syncthreads();
        for (int sft = 128; sft > 0; sft >>= 1) {
            if (tid < sft) {
                float o = sval[tid + sft]; int oi = sidx[tid + sft];
                if (o < sval[tid] || (o == sval[tid] && oi < sidx[tid])) {
                    sval[tid] = o; sidx[tid] = oi;
                }
            }
            __syncthreads();
        }
        if (tid == 0) out_idx[row] = (float)sidx[0];
        __syncthreads();
    }
}

// ======================= R4 fallback path (passing) =======================
__global__ void vq_znorm(const float* __restrict__ z, float* __restrict__ zzg) {
    int w    = (blockIdx.x * 256 + threadIdx.x) >> 6;
    int lane = threadIdx.x & 63;
    float4 v = ((const float4*)z)[(size_t)w * 64 + lane];
    double s = 0.0;
    s = fma((double)v.x, (double)v.x, s);
    s = fma((double)v.y, (double)v.y, s);
    s = fma((double)v.z, (double)v.z, s);
    s = fma((double)v.w, (double)v.w, s);
    #pragma unroll
    for (int off = 32; off > 0; off >>= 1) s += __shfl_xor(s, off);
    if (lane == 0) zzg[w] = (float)s;
}

__global__ void vq_cnorm(const float* __restrict__ cb, float* __restrict__ cnorm) {
    int w    = (blockIdx.x * 256 + threadIdx.x) >> 6;
    int lane = threadIdx.x & 63;
    float4 v = ((const float4*)cb)[(size_t)w * 64 + lane];
    double s = 0.0;
    s = fma((double)v.x, (double)v.x, s);
    s = fma((double)v.y, (double)v.y, s);
    s = fma((double)v.z, (double)v.z, s);
    s = fma((double)v.w, (double)v.w, s);
    #pragma unroll
    for (int off = 32; off > 0; off >>= 1) s += __shfl_xor(s, off);
    if (lane == 0) cnorm[w] = (float)s;
}

__global__ void vq_transpose(const float* __restrict__ cb, float* __restrict__ cbT) {
    int g = blockIdx.x * 256 + threadIdx.x;
    int d4 = g >> 10, code = g & 1023;
    ((float4*)cbT)[g] = ((const float4*)cb)[(size_t)code * 64 + d4];
}

#define TMF    64
#define TNF    256
#define NCHF   (KC / TNF)
#define SLICEF 4
#define NSLF   ((DIM/4) / SLICEF)
#define NRF    8
#define NCF    8

template<bool USE_T>
__global__ __launch_bounds__(256, 2)
void vq_scores(const float* __restrict__ z, const float* __restrict__ cb,
               const float* __restrict__ cbT, const float* __restrict__ cnorm,
               const float* __restrict__ zzg, float* __restrict__ out_idx)
{
    __shared__ float zA[TMF][DIM];
    __shared__ float cA[SLICEF][TNF][4];
    const int tid = threadIdx.x;
    const int tx = tid & 31;
    const int ty = tid >> 5;
    const int row0 = blockIdx.x * TMF;

    {
        const float4* zg = (const float4*)(z + (size_t)row0 * DIM);
        float4* zs = (float4*)&zA[0][0];
        #pragma unroll
        for (int t = 0; t < 16; ++t) zs[tid + t * 256] = zg[tid + t * 256];
    }

    float zzr[NRF];
    #pragma unroll
    for (int i = 0; i < NRF; ++i) zzr[i] = zzg[row0 + ty * NRF + i];

    float4 rn[4];
    #pragma unroll
    for (int t = 0; t < 4; ++t) {
        if (USE_T) rn[t] = ((const float4*)cbT)[(size_t)t * KC + tid];
        else       rn[t] = ((const float4*)cb)[(size_t)tid * 64 + t];
    }

    float rm1[NRF]; int ridx[NRF];
    #pragma unroll
    for (int i = 0; i < NRF; ++i) { rm1[i] = 3.0e38f; ridx[i] = 0; }

    #pragma unroll 1
    for (int nc = 0; nc < NCHF; ++nc) {
        float acc[NRF][NCF];
        #pragma unroll
        for (int i = 0; i < NRF; ++i)
            #pragma unroll
            for (int j = 0; j < NCF; ++j) acc[i][j] = 0.0f;

        #pragma unroll 1
        for (int s = 0; s < NSLF; ++s) {
            __syncthreads();
            #pragma unroll
            for (int t = 0; t < 4; ++t) *(float4*)&cA[t][tid][0] = rn[t];
            __syncthreads();

            {
                int ns = s + 1, nn = nc;
                if (ns == NSLF) { ns = 0; nn = nc + 1; }
                if (nn < NCHF) {
                    #pragma unroll
                    for (int t = 0; t < 4; ++t) {
                        int d4 = ns * SLICEF + t;
                        int code = nn * TNF + tid;
                        if (USE_T) rn[t] = ((const float4*)cbT)[(size_t)d4 * KC + code];
                        else       rn[t] = ((const float4*)cb)[(size_t)code * 64 + d4];
                    }
                }
            }

            #pragma unroll
            for (int d4l = 0; d4l < SLICEF; ++d4l) {
                const int d4 = s * SLICEF + d4l;
                float4 zr[NRF], cr[NCF];
                #pragma unroll
                for (int i = 0; i < NRF; ++i) zr[i] = *(const float4*)&zA[ty * NRF + i][d4 * 4];
                #pragma unroll
                for (int j = 0; j < NCF; ++j) cr[j] = *(const float4*)&cA[d4l][j * 32 + tx][0];
                #pragma unroll
                for (int i = 0; i < NRF; ++i)
                    #pragma unroll
                    for (int j = 0; j < NCF; ++j) {
                        acc[i][j] = fmaf(zr[i].x, cr[j].x, acc[i][j]);
                        acc[i][j] = fmaf(zr[i].y, cr[j].y, acc[i][j]);
                        acc[i][j] = fmaf(zr[i].z, cr[j].z, acc[i][j]);
                        acc[i][j] = fmaf(zr[i].w, cr[j].w, acc[i][j]);
                    }
            }
        }

        float cn[NCF];
        #pragma unroll
        for (int j = 0; j < NCF; ++j) cn[j] = cnorm[nc * TNF + j * 32 + tx];

        #pragma unroll
        for (int i = 0; i < NRF; ++i) {
            float c1 = 3.0e38f; int ci = 0;
            #pragma unroll
            for (int j = 0; j < NCF; ++j) {
                int code = nc * TNF + j * 32 + tx;
                float A  = zzr[i] + cn[j];
                float dq = A - 2.0f * acc[i][j];
                if (dq < c1) { c1 = dq; ci = code; }
            }
            #pragma unroll
            for (int off = 1; off < 32; off <<= 1) {
                float o1 = __shfl_xor(c1, off, 32);
                int  oi = __shfl_xor(ci, off, 32);
                if (o1 < c1 || (o1 == c1 && oi < ci)) { c1 = o1; ci = oi; }
            }
            if (c1 < rm1[i] || (c1 == rm1[i] && ci < ridx[i])) { rm1[i] = c1; ridx[i] = ci; }
        }
    }

    if (tx == 0) {
        #pragma unroll
        for (int i = 0; i < NRF; ++i) out_idx[row0 + ty * NRF + i] = (float)ridx[i];
    }
}

// ======================= shared output kernels =======================
__global__ __launch_bounds__(256)
void vq_outputs(const float* __restrict__ z, const float* __restrict__ cb,
                const float* __restrict__ out_idx, float* __restrict__ out,
                double* __restrict__ partials)
{
    __shared__ double sred[4];
    const int tid = threadIdx.x;
    double ls = 0.0;
    #pragma unroll 1
    for (int it = 0; it < 16; ++it) {
        size_t g = ((size_t)blockIdx.x * 16 + it) * 256 + tid;
        int row = (int)(g >> 6);
        int c4  = (int)(g & 63);
        float4 zv = ((const float4*)z)[g];
        int idx = (int)out_idx[row];
        float4 cv = ((const float4*)(cb + (size_t)idx * DIM))[c4];
        float4 o;
        o.x = zv.x + (cv.x - zv.x);
        o.y = zv.y + (cv.y - zv.y);
        o.z = zv.z + (cv.z - zv.z);
        o.w = zv.w + (cv.w - zv.w);
        ((float4*)out)[g] = o;
        float dx = zv.x - cv.x, dy = zv.y - cv.y, dz = zv.z - cv.z, dw = zv.w - cv.w;
        ls += (double)dx * dx + (double)dy * dy + (double)dz * dz + (double)dw * dw;
    }
    #pragma unroll
    for (int off = 32; off > 0; off >>= 1) ls += __shfl_down(ls, off);
    if ((tid & 63) == 0) sred[tid >> 6] = ls;
    __syncthreads();
    if (tid == 0) partials[blockIdx.x] = (sred[0] + sred[1]) + (sred[2] + sred[3]);
}

__global__ void vq_loss_final(const double* __restrict__ partials, float* __restrict__ out_loss) {
    __shared__ double s[256];
    const int tid = threadIdx.x;
    double a = 0.0;
    for (int i = tid; i < 2048; i += 256) a += partials[i];
    s[tid] = a;
    __syncthreads();
    for (int sft = 128; sft > 0; sft >>= 1) {
        if (tid < sft) s[tid] += s[tid + sft];
        __syncthreads();
    }
    if (tid == 0) {
        float mean = (float)(s[0] / (double)((size_t)N_TOK * DIM));
        out_loss[0] = 0.25f * mean + mean;
    }
}

extern "C" void kernel_launch(void* const* d_in, const int* in_sizes, int n_in,
                              void* d_out, int out_size, void* d_ws, size_t ws_size,
                              hipStream_t stream) {
    const float* z  = (const float*)d_in[0];
    const float* cb = (const float*)d_in[1];
    float* out = (float*)d_out;
    char* ws = (char*)d_ws;

    float* out_idx  = out + (size_t)N_TOK * DIM;
    float* out_loss = out_idx + N_TOK;

    if (ws_size >= WS_NEED) {
        unsigned short* z16   = (unsigned short*)(ws);
        float2*        m12    = (float2*)(ws + 67108864);
        int*           idxp   = (int*)(ws + 75497472);
        unsigned short* cb16  = (unsigned short*)(ws + 79691776);
        float*         cnorm  = (float*)(ws + 80216064);
        float*         zzg    = (float*)(ws + 80220160);
        unsigned int*  fcount = (unsigned int*)(ws + 80744448);
        int*           flist  = (int*)(ws + 80744512);
        double*        lparts = (double*)(ws + 81268800);

        vq_zero<<<1, 64, 0, stream>>>(fcount);
        vq_prep_z<<<N_TOK / 4, 256, 0, stream>>>(z, z16, zzg);
        vq_prep_cb<<<KC / 4, 256, 0, stream>>>(cb, cb16, cnorm);
        vq_scores_mfma<<<8 * 512, 256, 0, stream>>>(z16, cb16, cnorm, zzg, m12, idxp);
        vq_merge<<<N_TOK / 256, 256, 0, stream>>>(m12, idxp, out_idx, flist, fcount);
        vq_recheck<<<512, 256, 0, stream>>>(z, cb, cnorm, zzg, flist, fcount, out_idx);
        vq_outputs<<<2048, 256, 0, stream>>>(z, cb, out_idx, out, lparts);
        vq_loss_final<<<1, 256, 0, stream>>>(lparts, out_loss);
    } else {
        double* partials = (double*)(ws);
        float*  cnorm    = (float*)(ws + 16384);
        float*  zzg      = (float*)(ws + 20480);
        float*  cbT      = (float*)(ws + 544768);
        const bool useT  = ws_size >= (size_t)(544768 + KC * DIM * 4);

        vq_znorm<<<N_TOK / 4, 256, 0, stream>>>(z, zzg);
        vq_cnorm<<<KC / 4, 256, 0, stream>>>(cb, cnorm);
        if (useT) {
            vq_transpose<<<(KC * DIM / 4) / 256, 256, 0, stream>>>(cb, cbT);
            vq_scores<true><<<N_TOK / TMF, 256, 0, stream>>>(z, cb, cbT, cnorm, zzg, out_idx);
        } else {
            vq_scores<false><<<N_TOK / TMF, 256, 0, stream>>>(z, cb, cb, cnorm, zzg, out_idx);
        }
        vq_outputs<<<2048, 256, 0, stream>>>(z, cb, out_idx, out, partials);
        vq_loss_final<<<1, 256, 0, stream>>>(partials, out_loss);
    }
}

// Round 7
// 782.080 us; speedup vs baseline: 10.1763x; 10.1763x over previous
//
#include <hip/hip_runtime.h>

#define N_TOK 131072
#define KC    1024
#define DIM   256
#define GAP_THR 4e-4f
#define NTB   (N_TOK / 128)      // 1024 token blocks

typedef __attribute__((ext_vector_type(8)))  short bf16x8;
typedef __attribute__((ext_vector_type(16))) float f32x16;

__device__ __forceinline__ unsigned short f2bf(float f) {
    unsigned int u = __float_as_uint(f);
    unsigned int r = (u + 0x7fffu + ((u >> 16) & 1u)) >> 16;   // RNE
    return (unsigned short)r;
}

// ================= ws layout (MFMA path) =================
// 0         : z16   (bf16)  67108864 B
// 67108864  : m12   (float2) 8388608 B   [cb][token] (m1,m2)
// 75497472  : idxp  (int)    4194304 B   [cb][token]
// 79691776  : cb16  (bf16)    524288 B
// 80216064  : cnorm (f32)       4096 B
// 80220160  : zzg   (f32)     524288 B
// 80744448  : flag_count (u32)    64 B
// 80744512  : flag_list (int)  524288 B
// 81268800  : loss partials  16384 B
#define WS_NEED 81285184ull

__global__ void vq_zero(unsigned int* p) { if (threadIdx.x == 0) *p = 0u; }

// ---- prep: z -> bf16 + row norms (one wave per row) ----
__global__ void vq_prep_z(const float* __restrict__ z, unsigned short* __restrict__ z16,
                          float* __restrict__ zzg) {
    int row  = blockIdx.x * 4 + (threadIdx.x >> 6);
    int lane = threadIdx.x & 63;
    float4 v = ((const float4*)z)[(size_t)row * 64 + lane];
    ushort4 h;
    h.x = f2bf(v.x); h.y = f2bf(v.y); h.z = f2bf(v.z); h.w = f2bf(v.w);
    ((ushort4*)z16)[(size_t)row * 64 + lane] = h;
    double s = 0.0;
    s = fma((double)v.x, (double)v.x, s);
    s = fma((double)v.y, (double)v.y, s);
    s = fma((double)v.z, (double)v.z, s);
    s = fma((double)v.w, (double)v.w, s);
    #pragma unroll
    for (int off = 32; off > 0; off >>= 1) s += __shfl_xor(s, off);
    if (lane == 0) zzg[row] = (float)s;   // uniform per-row shift: argmin-invariant
}

__global__ void vq_prep_cb(const float* __restrict__ cb, unsigned short* __restrict__ cb16,
                           float* __restrict__ cnorm) {
    int code = blockIdx.x * 4 + (threadIdx.x >> 6);
    int lane = threadIdx.x & 63;
    float4 v = ((const float4*)cb)[(size_t)code * 64 + lane];
    ushort4 h;
    h.x = f2bf(v.x); h.y = f2bf(v.y); h.z = f2bf(v.z); h.w = f2bf(v.w);
    ((ushort4*)cb16)[(size_t)code * 64 + lane] = h;
    double s = 0.0;
    s = fma((double)v.x, (double)v.x, s);
    s = fma((double)v.y, (double)v.y, s);
    s = fma((double)v.z, (double)v.z, s);
    s = fma((double)v.w, (double)v.w, s);
    #pragma unroll
    for (int off = 32; off > 0; off >>= 1) s += __shfl_xor(s, off);
    if (lane == 0) cnorm[code] = (float)s;
}

// ---- MFMA scores: transposed GEMM (rows=codes, cols=tokens) ----
// Grid: 8 code-blocks x 1024 token-blocks (FULL token coverage — R6 bug was &511).
// Block: 256 thr = 4 waves (2 code-half x 2 token-half), tile 128 codes x 128 tokens.
// LDS tiles XOR-swizzled at b128 granularity: u32 unit du ^ ((row&7)<<2).
__global__ __launch_bounds__(256, 4)
void vq_scores_mfma(const unsigned short* __restrict__ z16, const unsigned short* __restrict__ cb16,
                    const float* __restrict__ cnorm, const float* __restrict__ zzg,
                    float2* __restrict__ m12, int* __restrict__ idxp)
{
    __shared__ unsigned int cA[128 * 32];   // 128 codes x 64 dims bf16 (16 KB)
    __shared__ unsigned int zA[128 * 32];   // 128 tokens x 64 dims bf16
    __shared__ float cns[128];

    const int tid = threadIdx.x;
    const int lane = tid & 63;
    const int l31 = lane & 31;
    const int hi = lane >> 5;
    const int wid = tid >> 6;
    const int wcode = wid >> 1;             // 0..1 : code half
    const int wtok = wid & 1;               // 0..1 : token half
    const int cbk = blockIdx.x >> 10;       // code block 0..7
    const int tb = blockIdx.x & (NTB - 1);  // token block 0..1023

    if (tid < 128) cns[tid] = cnorm[cbk * 128 + tid];

    f32x16 acc[2][2];
    #pragma unroll
    for (int a = 0; a < 2; ++a)
        #pragma unroll
        for (int b = 0; b < 2; ++b)
            #pragma unroll
            for (int r = 0; r < 16; ++r) acc[a][b][r] = 0.0f;

    #pragma unroll
    for (int kb = 0; kb < 4; ++kb) {
        if (kb) __syncthreads();
        #pragma unroll
        for (int i = 0; i < 16; ++i) {      // stage codes tile: 128 x 32 u32
            int g = tid + i * 256;
            int c = g >> 5, du = g & 31;
            cA[c * 32 + (du ^ ((c & 7) << 2))] =
                ((const unsigned int*)cb16)[(size_t)(cbk * 128 + c) * 128 + kb * 32 + du];
        }
        #pragma unroll
        for (int i = 0; i < 16; ++i) {      // stage tokens tile
            int g = tid + i * 256;
            int t = g >> 5, du = g & 31;
            zA[t * 32 + (du ^ ((t & 7) << 2))] =
                ((const unsigned int*)z16)[(size_t)(tb * 128 + t) * 128 + kb * 32 + du];
        }
        __syncthreads();

        #pragma unroll
        for (int ks = 0; ks < 4; ++ks) {
            bf16x8 af[2], bf[2];
            #pragma unroll
            for (int f = 0; f < 2; ++f) {
                int c = wcode * 64 + f * 32 + l31;
                af[f] = ((const bf16x8*)cA)[c * 8 + ((ks * 2 + hi) ^ (c & 7))];
                int t = wtok * 64 + f * 32 + l31;
                bf[f] = ((const bf16x8*)zA)[t * 8 + ((ks * 2 + hi) ^ (t & 7))];
            }
            #pragma unroll
            for (int a = 0; a < 2; ++a)
                #pragma unroll
                for (int b = 0; b < 2; ++b)
                    acc[a][b] = __builtin_amdgcn_mfma_f32_32x32x16_bf16(af[a], bf[b], acc[a][b], 0, 0, 0);
        }
    }

    __syncthreads();                        // MFMA reads done -> reuse cA as merge scratch
    float* sm1 = (float*)cA;                // [2][128]
    float* sm2 = sm1 + 256;                 // [2][128]
    int*   sid = (int*)(sm2 + 256);         // [2][128]

    // per token: top-2 + lowest-index over this wave's 64 codes, then half merge.
    // C layout (32x32): col=lane&31 (token), row=(reg&3)+8*(reg>>2)+4*hi (code)
    #pragma unroll
    for (int tf = 0; tf < 2; ++tf) {
        int ltok = wtok * 64 + tf * 32 + l31;
        float zz = zzg[tb * 128 + ltok];
        float m1 = 3.0e38f, m2 = 3.0e38f;
        #pragma unroll
        for (int cf = 0; cf < 2; ++cf)
            #pragma unroll
            for (int r = 0; r < 16; ++r) {
                int cl = wcode * 64 + cf * 32 + (r & 3) + 8 * (r >> 2) + 4 * hi;
                float A = zz + cns[cl];                       // fl(zz+cc)
                float dq = fmaf(acc[cf][tf][r], -2.0f, A);    // == fl(A - fl(2e)), 2e exact
                acc[cf][tf][r] = dq;                          // keep for idx pass
                float hv = fmaxf(m1, dq);
                m1 = fminf(m1, dq);
                m2 = fminf(m2, hv);                           // dup minima -> m2==m1 -> flagged
            }
        int idx = 0x7fffffff;
        #pragma unroll
        for (int cf = 0; cf < 2; ++cf)
            #pragma unroll
            for (int r = 0; r < 16; ++r) {
                int code = cbk * 128 + wcode * 64 + cf * 32 + (r & 3) + 8 * (r >> 2) + 4 * hi;
                idx = min(idx, (acc[cf][tf][r] == m1) ? code : 0x7fffffff);
            }
        // merge lane <-> lane^32 (same token, other code rows within this wave)
        float m1o = __shfl_xor(m1, 32);
        float m2o = __shfl_xor(m2, 32);
        int  idxo = __shfl_xor(idx, 32);
        float nm2 = fminf(fminf(m2, m2o), fmaxf(m1, m1o));
        int nidx = (m1o < m1 || (m1o == m1 && idxo < idx)) ? idxo : idx;
        float nm1 = fminf(m1, m1o);
        if (hi == 0) {
            sm1[wcode * 128 + ltok] = nm1;
            sm2[wcode * 128 + ltok] = nm2;
            sid[wcode * 128 + ltok] = nidx;
        }
    }
    __syncthreads();

    // merge the two code halves (128 threads, one per token) -> single global write
    if (tid < 128) {
        float a1 = sm1[tid],       a2 = sm2[tid];       int ai = sid[tid];
        float b1 = sm1[128 + tid], b2 = sm2[128 + tid]; int bi = sid[128 + tid];
        float m1, m2; int ix;
        if (b1 < a1 || (b1 == a1 && bi < ai)) { m1 = b1; ix = bi; m2 = fminf(b2, a1); }
        else                                   { m1 = a1; ix = ai; m2 = fminf(a2, b1); }
        size_t p = (size_t)cbk * N_TOK + tb * 128 + tid;
        m12[p] = make_float2(m1, m2);
        idxp[p] = ix;
    }
}

// ---- merge 8 code-block partials per token; flag near-ties ----
__global__ void vq_merge(const float2* __restrict__ m12, const int* __restrict__ idxp,
                         float* __restrict__ out_idx, int* __restrict__ flag_list,
                         unsigned int* __restrict__ flag_count)
{
    int t = blockIdx.x * 256 + threadIdx.x;
    float m1 = 3.0e38f, m2 = 3.0e38f; int i1 = 0x7fffffff;
    #pragma unroll
    for (int c = 0; c < 8; ++c) {
        float2 p = m12[(size_t)c * N_TOK + t];
        int ip = idxp[(size_t)c * N_TOK + t];
        if (p.x < m1 || (p.x == m1 && ip < i1)) {
            m2 = fminf(fminf(m1, p.y), m2);
            m1 = p.x; i1 = ip;
        } else {
            m2 = fminf(m2, p.x);
        }
    }
    out_idx[t] = (float)i1;
    if (!(m2 - m1 > GAP_THR)) {          // near-tie or NaN-safety -> exact recheck
        unsigned int p = atomicAdd(flag_count, 1u);
        flag_list[p] = t;
    }
}

// ---- exact f32-chain argmin for flagged rows, restricted to candidate code-blocks.
// A block's min (m12[c].x) lower-bounds every member's MFMA score, so blocks with
// block_min > global_min + GAP_THR provably cannot contain the np-f32 argmin.
__global__ __launch_bounds__(256)
void vq_recheck(const float* __restrict__ z, const float* __restrict__ cb,
                const float* __restrict__ cnorm, const float* __restrict__ zzg,
                const float2* __restrict__ m12, const int* __restrict__ flag_list,
                const unsigned int* __restrict__ flag_count, float* __restrict__ out_idx)
{
    __shared__ float zrow[DIM];
    __shared__ float sval[256];
    __shared__ int   sidx[256];
    const int tid = threadIdx.x;
    const unsigned int cnt = *flag_count;

    for (unsigned int f = blockIdx.x; f < cnt; f += gridDim.x) {
        const int row = flag_list[f];
        __syncthreads();                      // previous iter fully done with zrow
        zrow[tid] = z[(size_t)row * DIM + tid];
        __syncthreads();
        const float zz = zzg[row];

        // candidate blocks (computed redundantly per thread; deterministic)
        float bm1[8];
        float m1g = 3.0e38f;
        #pragma unroll
        for (int c = 0; c < 8; ++c) {
            bm1[c] = m12[(size_t)c * N_TOK + row].x;
            m1g = fminf(m1g, bm1[c]);
        }
        int cand[8]; int ncand = 0;
        #pragma unroll
        for (int c = 0; c < 8; ++c)
            if (bm1[c] <= m1g + GAP_THR) cand[ncand++] = c;

        float best = 3.0e38f; int bestc = 0x7fffffff;
        for (int p = 0; p < ncand; p += 2) {
            int sel = p + (tid >> 7);         // thr 0-127 -> cand[p], 128-255 -> cand[p+1]
            if (sel < ncand) {
                int code = cand[sel] * 128 + (tid & 127);
                const float4* c4 = (const float4*)(cb + (size_t)code * DIM);
                float e = 0.0f;
                #pragma unroll 16
                for (int d4 = 0; d4 < 64; ++d4) {        // strict sequential k = 0..255
                    float4 cv = c4[d4];
                    e = fmaf(zrow[d4 * 4 + 0], cv.x, e);
                    e = fmaf(zrow[d4 * 4 + 1], cv.y, e);
                    e = fmaf(zrow[d4 * 4 + 2], cv.z, e);
                    e = fmaf(zrow[d4 * 4 + 3], cv.w, e);
                }
                float A = zz + cnorm[code];               // fl(zz+cc)
                float dq = fmaf(e, -2.0f, A);             // == fl(A - fl(2e))
                if (dq < best || (dq == best && code < bestc)) { best = dq; bestc = code; }
            }
        }
        sval[tid] = best; sidx[tid] = bestc;
        __syncthreads();
        for (int sft = 128; sft > 0; sft >>= 1) {
            if (tid < sft) {
                float o = sval[tid + sft]; int oi = sidx[tid + sft];
                if (o < sval[tid] || (o == sval[tid] && oi < sidx[tid])) {
                    sval[tid] = o; sidx[tid] = oi;
                }
            }
            __syncthreads();
        }
        if (tid == 0) out_idx[row] = (float)sidx[0];
    }
}

// ======================= f32 fallback path (R4-passing) =======================
__global__ void vq_znorm(const float* __restrict__ z, float* __restrict__ zzg) {
    int w    = (blockIdx.x * 256 + threadIdx.x) >> 6;
    int lane = threadIdx.x & 63;
    float4 v = ((const float4*)z)[(size_t)w * 64 + lane];
    double s = 0.0;
    s = fma((double)v.x, (double)v.x, s);
    s = fma((double)v.y, (double)v.y, s);
    s = fma((double)v.z, (double)v.z, s);
    s = fma((double)v.w, (double)v.w, s);
    #pragma unroll
    for (int off = 32; off > 0; off >>= 1) s += __shfl_xor(s, off);
    if (lane == 0) zzg[w] = (float)s;
}

__global__ void vq_transpose(const float* __restrict__ cb, float* __restrict__ cbT) {
    int g = blockIdx.x * 256 + threadIdx.x;
    int d4 = g >> 10, code = g & 1023;
    ((float4*)cbT)[g] = ((const float4*)cb)[(size_t)code * 64 + d4];
}

#define TMF    64
#define TNF    256
#define NCHF   (KC / TNF)
#define SLICEF 4
#define NSLF   ((DIM/4) / SLICEF)
#define NRF    8
#define NCF    8

template<bool USE_T>
__global__ __launch_bounds__(256, 2)
void vq_scores(const float* __restrict__ z, const float* __restrict__ cb,
               const float* __restrict__ cbT, const float* __restrict__ cnorm,
               const float* __restrict__ zzg, float* __restrict__ out_idx)
{
    __shared__ float zA[TMF][DIM];
    __shared__ float cA[SLICEF][TNF][4];
    const int tid = threadIdx.x;
    const int tx = tid & 31;
    const int ty = tid >> 5;
    const int row0 = blockIdx.x * TMF;

    {
        const float4* zg = (const float4*)(z + (size_t)row0 * DIM);
        float4* zs = (float4*)&zA[0][0];
        #pragma unroll
        for (int t = 0; t < 16; ++t) zs[tid + t * 256] = zg[tid + t * 256];
    }

    float zzr[NRF];
    #pragma unroll
    for (int i = 0; i < NRF; ++i) zzr[i] = zzg[row0 + ty * NRF + i];

    float4 rn[4];
    #pragma unroll
    for (int t = 0; t < 4; ++t) {
        if (USE_T) rn[t] = ((const float4*)cbT)[(size_t)t * KC + tid];
        else       rn[t] = ((const float4*)cb)[(size_t)tid * 64 + t];
    }

    float rm1[NRF]; int ridx[NRF];
    #pragma unroll
    for (int i = 0; i < NRF; ++i) { rm1[i] = 3.0e38f; ridx[i] = 0; }

    #pragma unroll 1
    for (int nc = 0; nc < NCHF; ++nc) {
        float acc[NRF][NCF];
        #pragma unroll
        for (int i = 0; i < NRF; ++i)
            #pragma unroll
            for (int j = 0; j < NCF; ++j) acc[i][j] = 0.0f;

        #pragma unroll 1
        for (int s = 0; s < NSLF; ++s) {
            __syncthreads();
            #pragma unroll
            for (int t = 0; t < 4; ++t) *(float4*)&cA[t][tid][0] = rn[t];
            __syncthreads();

            {
                int ns = s + 1, nn = nc;
                if (ns == NSLF) { ns = 0; nn = nc + 1; }
                if (nn < NCHF) {
                    #pragma unroll
                    for (int t = 0; t < 4; ++t) {
                        int d4 = ns * SLICEF + t;
                        int code = nn * TNF + tid;
                        if (USE_T) rn[t] = ((const float4*)cbT)[(size_t)d4 * KC + code];
                        else       rn[t] = ((const float4*)cb)[(size_t)code * 64 + d4];
                    }
                }
            }

            #pragma unroll
            for (int d4l = 0; d4l < SLICEF; ++d4l) {
                const int d4 = s * SLICEF + d4l;
                float4 zr[NRF], cr[NCF];
                #pragma unroll
                for (int i = 0; i < NRF; ++i) zr[i] = *(const float4*)&zA[ty * NRF + i][d4 * 4];
                #pragma unroll
                for (int j = 0; j < NCF; ++j) cr[j] = *(const float4*)&cA[d4l][j * 32 + tx][0];
                #pragma unroll
                for (int i = 0; i < NRF; ++i)
                    #pragma unroll
                    for (int j = 0; j < NCF; ++j) {
                        acc[i][j] = fmaf(zr[i].x, cr[j].x, acc[i][j]);
                        acc[i][j] = fmaf(zr[i].y, cr[j].y, acc[i][j]);
                        acc[i][j] = fmaf(zr[i].z, cr[j].z, acc[i][j]);
                        acc[i][j] = fmaf(zr[i].w, cr[j].w, acc[i][j]);
                    }
            }
        }

        float cn[NCF];
        #pragma unroll
        for (int j = 0; j < NCF; ++j) cn[j] = cnorm[nc * TNF + j * 32 + tx];

        #pragma unroll
        for (int i = 0; i < NRF; ++i) {
            float c1 = 3.0e38f; int ci = 0;
            #pragma unroll
            for (int j = 0; j < NCF; ++j) {
                int code = nc * TNF + j * 32 + tx;
                float A  = zzr[i] + cn[j];
                float dq = A - 2.0f * acc[i][j];
                if (dq < c1) { c1 = dq; ci = code; }
            }
            #pragma unroll
            for (int off = 1; off < 32; off <<= 1) {
                float o1 = __shfl_xor(c1, off, 32);
                int  oi = __shfl_xor(ci, off, 32);
                if (o1 < c1 || (o1 == c1 && oi < ci)) { c1 = o1; ci = oi; }
            }
            if (c1 < rm1[i] || (c1 == rm1[i] && ci < ridx[i])) { rm1[i] = c1; ridx[i] = ci; }
        }
    }

    if (tx == 0) {
        #pragma unroll
        for (int i = 0; i < NRF; ++i) out_idx[row0 + ty * NRF + i] = (float)ridx[i];
    }
}

// ======================= shared output kernels =======================
__global__ __launch_bounds__(256)
void vq_outputs(const float* __restrict__ z, const float* __restrict__ cb,
                const float* __restrict__ out_idx, float* __restrict__ out,
                double* __restrict__ partials)
{
    __shared__ double sred[4];
    const int tid = threadIdx.x;
    double ls = 0.0;
    #pragma unroll 1
    for (int it = 0; it < 16; ++it) {
        size_t g = ((size_t)blockIdx.x * 16 + it) * 256 + tid;
        int row = (int)(g >> 6);
        int c4  = (int)(g & 63);
        float4 zv = ((const float4*)z)[g];
        int idx = (int)out_idx[row];
        float4 cv = ((const float4*)(cb + (size_t)idx * DIM))[c4];
        float4 o;
        o.x = zv.x + (cv.x - zv.x);
        o.y = zv.y + (cv.y - zv.y);
        o.z = zv.z + (cv.z - zv.z);
        o.w = zv.w + (cv.w - zv.w);
        ((float4*)out)[g] = o;
        float dx = zv.x - cv.x, dy = zv.y - cv.y, dz = zv.z - cv.z, dw = zv.w - cv.w;
        ls += (double)dx * dx + (double)dy * dy + (double)dz * dz + (double)dw * dw;
    }
    #pragma unroll
    for (int off = 32; off > 0; off >>= 1) ls += __shfl_down(ls, off);
    if ((tid & 63) == 0) sred[tid >> 6] = ls;
    __syncthreads();
    if (tid == 0) partials[blockIdx.x] = (sred[0] + sred[1]) + (sred[2] + sred[3]);
}

__global__ void vq_loss_final(const double* __restrict__ partials, float* __restrict__ out_loss) {
    __shared__ double s[256];
    const int tid = threadIdx.x;
    double a = 0.0;
    for (int i = tid; i < 2048; i += 256) a += partials[i];
    s[tid] = a;
    __syncthreads();
    for (int sft = 128; sft > 0; sft >>= 1) {
        if (tid < sft) s[tid] += s[tid + sft];
        __syncthreads();
    }
    if (tid == 0) {
        float mean = (float)(s[0] / (double)((size_t)N_TOK * DIM));
        out_loss[0] = 0.25f * mean + mean;
    }
}

extern "C" void kernel_launch(void* const* d_in, const int* in_sizes, int n_in,
                              void* d_out, int out_size, void* d_ws, size_t ws_size,
                              hipStream_t stream) {
    const float* z  = (const float*)d_in[0];
    const float* cb = (const float*)d_in[1];
    float* out = (float*)d_out;
    char* ws = (char*)d_ws;

    float* out_idx  = out + (size_t)N_TOK * DIM;
    float* out_loss = out_idx + N_TOK;

    if (ws_size >= WS_NEED) {
        unsigned short* z16   = (unsigned short*)(ws);
        float2*        m12    = (float2*)(ws + 67108864);
        int*           idxp   = (int*)(ws + 75497472);
        unsigned short* cb16  = (unsigned short*)(ws + 79691776);
        float*         cnorm  = (float*)(ws + 80216064);
        float*         zzg    = (float*)(ws + 80220160);
        unsigned int*  fcount = (unsigned int*)(ws + 80744448);
        int*           flist  = (int*)(ws + 80744512);
        double*        lparts = (double*)(ws + 81268800);

        vq_zero<<<1, 64, 0, stream>>>(fcount);
        vq_prep_z<<<N_TOK / 4, 256, 0, stream>>>(z, z16, zzg);
        vq_prep_cb<<<KC / 4, 256, 0, stream>>>(cb, cb16, cnorm);
        vq_scores_mfma<<<8 * NTB, 256, 0, stream>>>(z16, cb16, cnorm, zzg, m12, idxp);
        vq_merge<<<N_TOK / 256, 256, 0, stream>>>(m12, idxp, out_idx, flist, fcount);
        vq_recheck<<<2048, 256, 0, stream>>>(z, cb, cnorm, zzg, m12, flist, fcount, out_idx);
        vq_outputs<<<2048, 256, 0, stream>>>(z, cb, out_idx, out, lparts);
        vq_loss_final<<<1, 256, 0, stream>>>(lparts, out_loss);
    } else {
        double* partials = (double*)(ws);
        float*  cnorm    = (float*)(ws + 16384);
        float*  zzg      = (float*)(ws + 20480);
        float*  cbT      = (float*)(ws + 544768);
        const bool useT  = ws_size >= (size_t)(544768 + KC * DIM * 4);

        vq_znorm<<<N_TOK / 4, 256, 0, stream>>>(z, zzg);
        vq_prep_cb<<<KC / 4, 256, 0, stream>>>(cb, (unsigned short*)(ws + 20480 - 4096), cnorm); // unused cb16 slot-safe? no:
        // (fallback keeps its own cnorm fill)
        vq_znorm<<<KC / 4, 256, 0, stream>>>(cb, cnorm);
        if (useT) {
            vq_transpose<<<(KC * DIM / 4) / 256, 256, 0, stream>>>(cb, cbT);
            vq_scores<true><<<N_TOK / TMF, 256, 0, stream>>>(z, cb, cbT, cnorm, zzg, out_idx);
        } else {
            vq_scores<false><<<N_TOK / TMF, 256, 0, stream>>>(z, cb, cb, cnorm, zzg, out_idx);
        }
        vq_outputs<<<2048, 256, 0, stream>>>(z, cb, out_idx, out, partials);
        vq_loss_final<<<1, 256, 0, stream>>>(partials, out_loss);
    }
}

// Round 8
// 520.020 us; speedup vs baseline: 15.3046x; 1.5039x over previous
//
#include <hip/hip_runtime.h>

#define N_TOK 131072
#define KC    1024
#define DIM   256
#define GAP_THR 4e-4f
#define NBLK  (N_TOK / 128)      // 1024 token blocks

typedef __attribute__((ext_vector_type(8)))  short bf16x8;
typedef __attribute__((ext_vector_type(16))) float f32x16;

__device__ __forceinline__ unsigned short f2bf(float f) {
    unsigned int u = __float_as_uint(f);
    unsigned int r = (u + 0x7fffu + ((u >> 16) & 1u)) >> 16;   // RNE
    return (unsigned short)r;
}

// ================= ws layout =================
// 0       : cb16  (bf16)   524288 B
// 524288  : cnorm (f32)      4096 B
// 528384  : fcount (u32)       64 B
// 528448  : flist (int)    524288 B   entry = row | (candidate_mask << 17)
// 1052736 : lparts (f64)     8192 B
#define WS_NEED 1060928ull

__global__ void vq_zero(unsigned int* p) { if (threadIdx.x == 0) *p = 0u; }

// cb -> bf16 + f64 norms (one wave per code)
__global__ void vq_prep_cb(const float* __restrict__ cb, unsigned short* __restrict__ cb16,
                           float* __restrict__ cnorm) {
    int code = blockIdx.x * 4 + (threadIdx.x >> 6);
    int lane = threadIdx.x & 63;
    float4 v = ((const float4*)cb)[(size_t)code * 64 + lane];
    ushort4 h;
    h.x = f2bf(v.x); h.y = f2bf(v.y); h.z = f2bf(v.z); h.w = f2bf(v.w);
    ((ushort4*)cb16)[(size_t)code * 64 + lane] = h;
    double s = 0.0;
    s = fma((double)v.x, (double)v.x, s);
    s = fma((double)v.y, (double)v.y, s);
    s = fma((double)v.z, (double)v.z, s);
    s = fma((double)v.w, (double)v.w, s);
    #pragma unroll
    for (int off = 32; off > 0; off >>= 1) s += __shfl_xor(s, off);
    if (lane == 0) cnorm[code] = (float)s;
}

// ---- Fused: bf16 MFMA scores over ALL 1024 codes + argmin/top-2 + flagging
//      + z_st output + loss partial. One pass over z (HBM) per block.
// Block: 256 thr = 4 waves (2 wcode x 2 wtok); per wave 64 codes x 64 tokens per cbk.
// B (tokens) lives in registers for the whole kernel: bfr[f][kb][ks] bf16x8.
// A (codes) staged per cbk in 64KB swizzled LDS from L2-resident cb16.
__global__ __launch_bounds__(256, 2)
void vq_scores_fused(const float* __restrict__ z, const unsigned short* __restrict__ cb16,
                     const float* __restrict__ cb, const float* __restrict__ cnorm,
                     float* __restrict__ out, float* __restrict__ out_idx,
                     int* __restrict__ flist, unsigned int* __restrict__ fcount,
                     double* __restrict__ lparts)
{
    __shared__ uint4  cA[128 * 32];     // 64 KB : 128 codes x 256 dims bf16, 16B-unit swizzled
    __shared__ float  cnsL[KC];         // 4 KB
    __shared__ float  bm1L[8][128];     // per-cbk per-token block-min
    __shared__ float  gm1[128], gm2[128];
    __shared__ int    gid[128];
    __shared__ double sredD[4];

    const int tid = threadIdx.x;
    const int lane = tid & 63;
    const int l31 = lane & 31;
    const int hi  = lane >> 5;
    const int wid = tid >> 6;
    const int wcode = wid >> 1;
    const int wtok  = wid & 1;
    const int tb = blockIdx.x;

    #pragma unroll
    for (int k = 0; k < 4; ++k) cnsL[tid + k * 256] = cnorm[tid + k * 256];
    if (tid < 128) { gm1[tid] = 3.0e38f; gm2[tid] = 3.0e38f; gid[tid] = 0x7fffffff; }

    // ---- B fragments from global f32 (lane hi-pairs consume full 64B lines) + zz ----
    bf16x8 bfr[2][4][4];
    float zzr[2];
    #pragma unroll
    for (int f = 0; f < 2; ++f) {
        const int t = tb * 128 + wtok * 64 + f * 32 + l31;
        const float* zr = z + (size_t)t * DIM;
        double s = 0.0;
        #pragma unroll
        for (int kb = 0; kb < 4; ++kb)
            #pragma unroll
            for (int ks = 0; ks < 4; ++ks) {
                const int d0 = kb * 64 + ks * 16 + hi * 8;
                float4 x = *(const float4*)(zr + d0);
                float4 y = *(const float4*)(zr + d0 + 4);
                s = fma((double)x.x, (double)x.x, s);
                s = fma((double)x.y, (double)x.y, s);
                s = fma((double)x.z, (double)x.z, s);
                s = fma((double)x.w, (double)x.w, s);
                s = fma((double)y.x, (double)y.x, s);
                s = fma((double)y.y, (double)y.y, s);
                s = fma((double)y.z, (double)y.z, s);
                s = fma((double)y.w, (double)y.w, s);
                bf16x8 v;
                v[0] = (short)f2bf(x.x); v[1] = (short)f2bf(x.y);
                v[2] = (short)f2bf(x.z); v[3] = (short)f2bf(x.w);
                v[4] = (short)f2bf(y.x); v[5] = (short)f2bf(y.y);
                v[6] = (short)f2bf(y.z); v[7] = (short)f2bf(y.w);
                bfr[f][kb][ks] = v;
            }
        s += __shfl_xor(s, 32);          // partner lane holds the other dim-half
        zzr[f] = (float)s;               // uniform per-row shift: argmin-invariant
    }

    // ---- loop all 8 code blocks ----
    #pragma unroll 1
    for (int cbk = 0; cbk < 8; ++cbk) {
        __syncthreads();                 // cA/scratch free; init visible on iter 0
        #pragma unroll
        for (int i = 0; i < 16; ++i) {   // stage 64 KB code tile, swizzled 16B units
            int g = tid + i * 256;
            int c = g >> 5, u = g & 31;
            cA[c * 32 + (u ^ (c & 7))] = ((const uint4*)cb16)[(size_t)(cbk * 128 + c) * 32 + u];
        }
        __syncthreads();

        f32x16 acc[2][2];
        #pragma unroll
        for (int a = 0; a < 2; ++a)
            #pragma unroll
            for (int b = 0; b < 2; ++b)
                #pragma unroll
                for (int r = 0; r < 16; ++r) acc[a][b][r] = 0.0f;

        #pragma unroll
        for (int kb = 0; kb < 4; ++kb)
            #pragma unroll
            for (int ks = 0; ks < 4; ++ks) {
                bf16x8 af[2];
                #pragma unroll
                for (int a = 0; a < 2; ++a) {
                    int c = wcode * 64 + a * 32 + l31;
                    af[a] = ((const bf16x8*)cA)[c * 32 + ((kb * 8 + ks * 2 + hi) ^ (c & 7))];
                }
                #pragma unroll
                for (int a = 0; a < 2; ++a)
                    #pragma unroll
                    for (int b = 0; b < 2; ++b)
                        acc[a][b] = __builtin_amdgcn_mfma_f32_32x32x16_bf16(af[a], bfr[b][kb][ks], acc[a][b], 0, 0, 0);
            }

        // epilogue: per-lane top-2 over 32 codes, lane^32 merge, stash to scratch
        float* sm1 = (float*)cA;                 // cA reusable until next stage
        float* sm2 = sm1 + 256;
        int*   sid = (int*)(sm2 + 256);
        #pragma unroll
        for (int tf = 0; tf < 2; ++tf) {
            float c1 = 3.0e38f, c2 = 3.0e38f;
            #pragma unroll
            for (int cf = 0; cf < 2; ++cf)
                #pragma unroll
                for (int r = 0; r < 16; ++r) {
                    int cl = wcode * 64 + cf * 32 + (r & 3) + 8 * (r >> 2) + 4 * hi;
                    float A  = zzr[tf] + cnsL[cbk * 128 + cl];     // fl(zz+cc)
                    float dq = fmaf(acc[cf][tf][r], -2.0f, A);     // fl(A - fl(2e))
                    acc[cf][tf][r] = dq;
                    float hv = fmaxf(c1, dq);
                    c1 = fminf(c1, dq);
                    c2 = fminf(c2, hv);
                }
            int ci = 0x7fffffff;
            #pragma unroll
            for (int cf = 0; cf < 2; ++cf)
                #pragma unroll
                for (int r = 0; r < 16; ++r) {
                    int code = cbk * 128 + wcode * 64 + cf * 32 + (r & 3) + 8 * (r >> 2) + 4 * hi;
                    ci = min(ci, (acc[cf][tf][r] == c1) ? code : 0x7fffffff);
                }
            float o1 = __shfl_xor(c1, 32);
            float o2 = __shfl_xor(c2, 32);
            int  oi = __shfl_xor(ci, 32);
            float nm2 = fminf(fminf(c2, o2), fmaxf(c1, o1));
            int  ni = (o1 < c1 || (o1 == c1 && oi < ci)) ? oi : ci;
            float nm1 = fminf(c1, o1);
            if (hi == 0) {
                int lt = wtok * 64 + tf * 32 + l31;
                sm1[wcode * 128 + lt] = nm1;
                sm2[wcode * 128 + lt] = nm2;
                sid[wcode * 128 + lt] = ni;
            }
        }
        __syncthreads();
        if (tid < 128) {                  // merge wcode halves + update running state
            float a1 = sm1[tid],       a2 = sm2[tid];       int ai = sid[tid];
            float b1 = sm1[128 + tid], b2 = sm2[128 + tid]; int bi = sid[128 + tid];
            float m1, m2; int ix;
            if (b1 < a1 || (b1 == a1 && bi < ai)) { m1 = b1; ix = bi; m2 = fminf(b2, a1); }
            else                                   { m1 = a1; ix = ai; m2 = fminf(a2, b1); }
            bm1L[cbk][tid] = m1;
            float g1 = gm1[tid], g2 = gm2[tid]; int gi = gid[tid];
            float ng2 = fminf(fminf(g2, m2), fmaxf(g1, m1));
            if (m1 < g1 || (m1 == g1 && ix < gi)) { g1 = m1; gi = ix; }
            gm1[tid] = g1; gm2[tid] = ng2; gid[tid] = gi;
        }
    }
    __syncthreads();

    // ---- flag + provisional index write ----
    if (tid < 128) {
        int row = tb * 128 + tid;
        out_idx[row] = (float)gid[tid];
        float g1 = gm1[tid];
        float gap = gm2[tid] - g1;
        int mask = 0;
        #pragma unroll
        for (int c = 0; c < 8; ++c) mask |= (bm1L[c][tid] <= g1 + GAP_THR) ? (1 << c) : 0;
        if (!(gap > GAP_THR)) {           // near-tie or NaN safety -> exact recheck
            unsigned int p = atomicAdd(fcount, 1u);
            flist[p] = row | (mask << 17);
        }
    }
    __syncthreads();

    // ---- fused z_st + loss (z tile re-read is L2-hot) ----
    double ls = 0.0;
    const float4* z4  = (const float4*)z;
    const float4* cb4 = (const float4*)cb;
    float4* out4 = (float4*)out;
    #pragma unroll 4
    for (int it = 0; it < 32; ++it) {
        int fi = tid + it * 256;
        int row = fi >> 6, c4 = fi & 63;
        float4 zv = z4[(size_t)(tb * 128 + row) * 64 + c4];
        int idx = gid[row];
        float4 cv = cb4[(size_t)idx * 64 + c4];
        float4 o;
        o.x = zv.x + (cv.x - zv.x);
        o.y = zv.y + (cv.y - zv.y);
        o.z = zv.z + (cv.z - zv.z);
        o.w = zv.w + (cv.w - zv.w);
        out4[(size_t)(tb * 128 + row) * 64 + c4] = o;
        float dx = zv.x - cv.x, dy = zv.y - cv.y, dz = zv.z - cv.z, dw = zv.w - cv.w;
        ls += (double)dx * dx + (double)dy * dy + (double)dz * dz + (double)dw * dw;
    }
    #pragma unroll
    for (int off = 32; off > 0; off >>= 1) ls += __shfl_down(ls, off);
    if (lane == 0) sredD[wid] = ls;
    __syncthreads();
    if (tid == 0) lparts[tb] = (sredD[0] + sredD[1]) + (sredD[2] + sredD[3]);
}

// ---- exact np-f32-chain argmin for flagged rows over candidate blocks only;
//      rewrites out_idx AND the z_st row (loss shift is ~1e-10, negligible).
__global__ __launch_bounds__(256)
void vq_recheck(const float* __restrict__ z, const float* __restrict__ cb,
                const float* __restrict__ cnorm, const int* __restrict__ flist,
                const unsigned int* __restrict__ fcount,
                float* __restrict__ out, float* __restrict__ out_idx)
{
    __shared__ float  zrow[DIM];
    __shared__ double rd[256];
    __shared__ float  sval[256];
    __shared__ int    sidx[256];
    __shared__ int    bests;
    const int tid = threadIdx.x;
    const unsigned int cnt = *fcount;

    for (unsigned int fq = blockIdx.x; fq < cnt; fq += gridDim.x) {
        int e = flist[fq];
        int row  = e & 0x1FFFF;
        int mask = ((unsigned int)e) >> 17;
        __syncthreads();                              // previous iter fully done
        zrow[tid] = z[(size_t)row * DIM + tid];
        __syncthreads();
        rd[tid] = (double)zrow[tid] * (double)zrow[tid];
        __syncthreads();
        for (int s = 128; s > 0; s >>= 1) { if (tid < s) rd[tid] += rd[tid + s]; __syncthreads(); }
        const float zz = (float)rd[0];

        int cand[8]; int nc = 0;
        #pragma unroll
        for (int c = 0; c < 8; ++c) if (mask & (1 << c)) cand[nc++] = c;

        float best = 3.0e38f; int bi = 0x7fffffff;
        for (int p = 0; p < nc; p += 2) {
            int sel = p + (tid >> 7);                 // thr 0-127 -> cand[p], 128-255 -> cand[p+1]
            if (sel < nc) {
                int code = cand[sel] * 128 + (tid & 127);
                const float4* c4p = (const float4*)(cb + (size_t)code * DIM);
                float ev = 0.0f;
                #pragma unroll 16
                for (int d4 = 0; d4 < 64; ++d4) {     // strict sequential k = 0..255
                    float4 cv = c4p[d4];
                    ev = fmaf(zrow[d4 * 4 + 0], cv.x, ev);
                    ev = fmaf(zrow[d4 * 4 + 1], cv.y, ev);
                    ev = fmaf(zrow[d4 * 4 + 2], cv.z, ev);
                    ev = fmaf(zrow[d4 * 4 + 3], cv.w, ev);
                }
                float A  = zz + cnorm[code];
                float dq = fmaf(ev, -2.0f, A);
                if (dq < best || (dq == best && code < bi)) { best = dq; bi = code; }
            }
        }
        sval[tid] = best; sidx[tid] = bi;
        __syncthreads();
        for (int s = 128; s > 0; s >>= 1) {
            if (tid < s) {
                float o = sval[tid + s]; int oi = sidx[tid + s];
                if (o < sval[tid] || (o == sval[tid] && oi < sidx[tid])) {
                    sval[tid] = o; sidx[tid] = oi;
                }
            }
            __syncthreads();
        }
        if (tid == 0) { out_idx[row] = (float)sidx[0]; bests = sidx[0]; }
        __syncthreads();
        const int b = bests;
        if (tid < 64) {                               // rewrite z_st row with final code
            float4 zv = ((const float4*)z)[(size_t)row * 64 + tid];
            float4 cv = ((const float4*)cb)[(size_t)b * 64 + tid];
            float4 o;
            o.x = zv.x + (cv.x - zv.x);
            o.y = zv.y + (cv.y - zv.y);
            o.z = zv.z + (cv.z - zv.z);
            o.w = zv.w + (cv.w - zv.w);
            ((float4*)out)[(size_t)row * 64 + tid] = o;
        }
    }
}

__global__ void vq_loss_final(const double* __restrict__ lparts, float* __restrict__ out_loss) {
    __shared__ double s[256];
    const int tid = threadIdx.x;
    double a = 0.0;
    for (int i = tid; i < NBLK; i += 256) a += lparts[i];
    s[tid] = a;
    __syncthreads();
    for (int sft = 128; sft > 0; sft >>= 1) {
        if (tid < sft) s[tid] += s[tid + sft];
        __syncthreads();
    }
    if (tid == 0) {
        float mean = (float)(s[0] / (double)((size_t)N_TOK * DIM));
        out_loss[0] = 0.25f * mean + mean;   // commit + codebook, reference op order
    }
}

extern "C" void kernel_launch(void* const* d_in, const int* in_sizes, int n_in,
                              void* d_out, int out_size, void* d_ws, size_t ws_size,
                              hipStream_t stream) {
    const float* z  = (const float*)d_in[0];
    const float* cb = (const float*)d_in[1];
    float* out = (float*)d_out;
    char* ws = (char*)d_ws;

    unsigned short* cb16  = (unsigned short*)(ws);
    float*         cnorm  = (float*)(ws + 524288);
    unsigned int*  fcount = (unsigned int*)(ws + 528384);
    int*           flist  = (int*)(ws + 528448);
    double*        lparts = (double*)(ws + 1052736);

    float* out_idx  = out + (size_t)N_TOK * DIM;
    float* out_loss = out_idx + N_TOK;

    vq_zero<<<1, 64, 0, stream>>>(fcount);
    vq_prep_cb<<<KC / 4, 256, 0, stream>>>(cb, cb16, cnorm);
    vq_scores_fused<<<NBLK, 256, 0, stream>>>(z, cb16, cb, cnorm, out, out_idx,
                                              flist, fcount, lparts);
    vq_recheck<<<1024, 256, 0, stream>>>(z, cb, cnorm, flist, fcount, out, out_idx);
    vq_loss_final<<<1, 256, 0, stream>>>(lparts, out_loss);
}

// Round 9
// 432.731 us; speedup vs baseline: 18.3917x; 1.2017x over previous
//
#include <hip/hip_runtime.h>

#define N_TOK 131072
#define KC    1024
#define DIM   256
#define GAP_THR 4e-4f
#define NBLK  (N_TOK / 128)      // 1024 token blocks

typedef __attribute__((ext_vector_type(8)))  short bf16x8;
typedef __attribute__((ext_vector_type(16))) float f32x16;

__device__ __forceinline__ unsigned short f2bf(float f) {
    unsigned int u = __float_as_uint(f);
    unsigned int r = (u + 0x7fffu + ((u >> 16) & 1u)) >> 16;   // RNE
    return (unsigned short)r;
}

// ================= ws layout =================
// 0       : cb16  (bf16)      524288 B
// 524288  : cnorm (f32)         4096 B
// 528384  : cbT   (f32)      1048576 B   cbT[d4][code][4] transposed codebook
// 1576960 : fcount (u32)          64 B
// 1577024 : flist (int)      4194304 B   entry = row | (blk << 17), one per pair
// 5771328 : rck   (u64)      1048576 B   per-row (dq_bits<<32 | code) atomicMin
// 6819904 : lparts (f64)        8192 B
#define WS_NEED 6828096ull

__global__ void vq_zero(unsigned int* p) { if (threadIdx.x == 0) *p = 0u; }

// cb -> bf16 + f64 norms (one wave per code)
__global__ void vq_prep_cb(const float* __restrict__ cb, unsigned short* __restrict__ cb16,
                           float* __restrict__ cnorm) {
    int code = blockIdx.x * 4 + (threadIdx.x >> 6);
    int lane = threadIdx.x & 63;
    float4 v = ((const float4*)cb)[(size_t)code * 64 + lane];
    ushort4 h;
    h.x = f2bf(v.x); h.y = f2bf(v.y); h.z = f2bf(v.z); h.w = f2bf(v.w);
    ((ushort4*)cb16)[(size_t)code * 64 + lane] = h;
    double s = 0.0;
    s = fma((double)v.x, (double)v.x, s);
    s = fma((double)v.y, (double)v.y, s);
    s = fma((double)v.z, (double)v.z, s);
    s = fma((double)v.w, (double)v.w, s);
    #pragma unroll
    for (int off = 32; off > 0; off >>= 1) s += __shfl_xor(s, off);
    if (lane == 0) cnorm[code] = (float)s;
}

// cbT[d4][code][4] = cb[code][4*d4 .. 4*d4+4)  (coalesced writes)
__global__ void vq_transpose(const float* __restrict__ cb, float* __restrict__ cbT) {
    int g = blockIdx.x * 256 + threadIdx.x;       // [0, 65536)
    int d4 = g >> 10, code = g & 1023;
    ((float4*)cbT)[g] = ((const float4*)cb)[(size_t)code * 64 + d4];
}

// ---- Fused: bf16 MFMA scores over ALL 1024 codes + argmin/top-2 + pair flagging
//      + z_st output + loss partial. One HBM pass over z per block. (R8-passing core.)
__global__ __launch_bounds__(256, 2)
void vq_scores_fused(const float* __restrict__ z, const unsigned short* __restrict__ cb16,
                     const float* __restrict__ cb, const float* __restrict__ cnorm,
                     float* __restrict__ out, float* __restrict__ out_idx,
                     int* __restrict__ flist, unsigned int* __restrict__ fcount,
                     unsigned long long* __restrict__ rck, double* __restrict__ lparts)
{
    __shared__ uint4  cA[128 * 32];     // 64 KB : 128 codes x 256 dims bf16, 16B-unit swizzled
    __shared__ float  cnsL[KC];         // 4 KB
    __shared__ float  bm1L[8][128];     // per-cbk per-token block-min
    __shared__ float  gm1[128], gm2[128];
    __shared__ int    gid[128];
    __shared__ double sredD[4];

    const int tid = threadIdx.x;
    const int lane = tid & 63;
    const int l31 = lane & 31;
    const int hi  = lane >> 5;
    const int wid = tid >> 6;
    const int wcode = wid >> 1;
    const int wtok  = wid & 1;
    const int tb = blockIdx.x;

    #pragma unroll
    for (int k = 0; k < 4; ++k) cnsL[tid + k * 256] = cnorm[tid + k * 256];
    if (tid < 128) { gm1[tid] = 3.0e38f; gm2[tid] = 3.0e38f; gid[tid] = 0x7fffffff; }

    // ---- B fragments from global f32 (lane hi-pairs consume full 64B lines) + zz ----
    bf16x8 bfr[2][4][4];
    float zzr[2];
    #pragma unroll
    for (int f = 0; f < 2; ++f) {
        const int t = tb * 128 + wtok * 64 + f * 32 + l31;
        const float* zr = z + (size_t)t * DIM;
        double s = 0.0;
        #pragma unroll
        for (int kb = 0; kb < 4; ++kb)
            #pragma unroll
            for (int ks = 0; ks < 4; ++ks) {
                const int d0 = kb * 64 + ks * 16 + hi * 8;
                float4 x = *(const float4*)(zr + d0);
                float4 y = *(const float4*)(zr + d0 + 4);
                s = fma((double)x.x, (double)x.x, s);
                s = fma((double)x.y, (double)x.y, s);
                s = fma((double)x.z, (double)x.z, s);
                s = fma((double)x.w, (double)x.w, s);
                s = fma((double)y.x, (double)y.x, s);
                s = fma((double)y.y, (double)y.y, s);
                s = fma((double)y.z, (double)y.z, s);
                s = fma((double)y.w, (double)y.w, s);
                bf16x8 v;
                v[0] = (short)f2bf(x.x); v[1] = (short)f2bf(x.y);
                v[2] = (short)f2bf(x.z); v[3] = (short)f2bf(x.w);
                v[4] = (short)f2bf(y.x); v[5] = (short)f2bf(y.y);
                v[6] = (short)f2bf(y.z); v[7] = (short)f2bf(y.w);
                bfr[f][kb][ks] = v;
            }
        s += __shfl_xor(s, 32);          // partner lane holds the other dim-half
        zzr[f] = (float)s;               // uniform per-row shift: argmin-invariant
    }

    // ---- loop all 8 code blocks ----
    #pragma unroll 1
    for (int cbk = 0; cbk < 8; ++cbk) {
        __syncthreads();                 // cA/scratch free; init visible on iter 0
        #pragma unroll
        for (int i = 0; i < 16; ++i) {   // stage 64 KB code tile, swizzled 16B units
            int g = tid + i * 256;
            int c = g >> 5, u = g & 31;
            cA[c * 32 + (u ^ (c & 7))] = ((const uint4*)cb16)[(size_t)(cbk * 128 + c) * 32 + u];
        }
        __syncthreads();

        f32x16 acc[2][2];
        #pragma unroll
        for (int a = 0; a < 2; ++a)
            #pragma unroll
            for (int b = 0; b < 2; ++b)
                #pragma unroll
                for (int r = 0; r < 16; ++r) acc[a][b][r] = 0.0f;

        #pragma unroll
        for (int kb = 0; kb < 4; ++kb)
            #pragma unroll
            for (int ks = 0; ks < 4; ++ks) {
                bf16x8 af[2];
                #pragma unroll
                for (int a = 0; a < 2; ++a) {
                    int c = wcode * 64 + a * 32 + l31;
                    af[a] = ((const bf16x8*)cA)[c * 32 + ((kb * 8 + ks * 2 + hi) ^ (c & 7))];
                }
                #pragma unroll
                for (int a = 0; a < 2; ++a)
                    #pragma unroll
                    for (int b = 0; b < 2; ++b)
                        acc[a][b] = __builtin_amdgcn_mfma_f32_32x32x16_bf16(af[a], bfr[b][kb][ks], acc[a][b], 0, 0, 0);
            }

        // epilogue: per-lane top-2 over 32 codes, lane^32 merge, stash to scratch
        float* sm1 = (float*)cA;                 // cA reusable until next stage
        float* sm2 = sm1 + 256;
        int*   sid = (int*)(sm2 + 256);
        #pragma unroll
        for (int tf = 0; tf < 2; ++tf) {
            float c1 = 3.0e38f, c2 = 3.0e38f;
            #pragma unroll
            for (int cf = 0; cf < 2; ++cf)
                #pragma unroll
                for (int r = 0; r < 16; ++r) {
                    int cl = wcode * 64 + cf * 32 + (r & 3) + 8 * (r >> 2) + 4 * hi;
                    float A  = zzr[tf] + cnsL[cbk * 128 + cl];     // fl(zz+cc)
                    float dq = fmaf(acc[cf][tf][r], -2.0f, A);     // fl(A - fl(2e))
                    acc[cf][tf][r] = dq;
                    float hv = fmaxf(c1, dq);
                    c1 = fminf(c1, dq);
                    c2 = fminf(c2, hv);
                }
            int ci = 0x7fffffff;
            #pragma unroll
            for (int cf = 0; cf < 2; ++cf)
                #pragma unroll
                for (int r = 0; r < 16; ++r) {
                    int code = cbk * 128 + wcode * 64 + cf * 32 + (r & 3) + 8 * (r >> 2) + 4 * hi;
                    ci = min(ci, (acc[cf][tf][r] == c1) ? code : 0x7fffffff);
                }
            float o1 = __shfl_xor(c1, 32);
            float o2 = __shfl_xor(c2, 32);
            int  oi = __shfl_xor(ci, 32);
            float nm2 = fminf(fminf(c2, o2), fmaxf(c1, o1));
            int  ni = (o1 < c1 || (o1 == c1 && oi < ci)) ? oi : ci;
            float nm1 = fminf(c1, o1);
            if (hi == 0) {
                int lt = wtok * 64 + tf * 32 + l31;
                sm1[wcode * 128 + lt] = nm1;
                sm2[wcode * 128 + lt] = nm2;
                sid[wcode * 128 + lt] = ni;
            }
        }
        __syncthreads();
        if (tid < 128) {                  // merge wcode halves + update running state
            float a1 = sm1[tid],       a2 = sm2[tid];       int ai = sid[tid];
            float b1 = sm1[128 + tid], b2 = sm2[128 + tid]; int bi = sid[128 + tid];
            float m1, m2; int ix;
            if (b1 < a1 || (b1 == a1 && bi < ai)) { m1 = b1; ix = bi; m2 = fminf(b2, a1); }
            else                                   { m1 = a1; ix = ai; m2 = fminf(a2, b1); }
            bm1L[cbk][tid] = m1;
            float g1 = gm1[tid], g2 = gm2[tid]; int gi = gid[tid];
            float ng2 = fminf(fminf(g2, m2), fmaxf(g1, m1));
            if (m1 < g1 || (m1 == g1 && ix < gi)) { g1 = m1; gi = ix; }
            gm1[tid] = g1; gm2[tid] = ng2; gid[tid] = gi;
        }
    }
    __syncthreads();

    // ---- flag pairs + provisional index write ----
    if (tid < 128) {
        int row = tb * 128 + tid;
        out_idx[row] = (float)gid[tid];
        float g1 = gm1[tid];
        float gap = gm2[tid] - g1;
        if (!(gap > GAP_THR)) {           // near-tie or NaN safety -> exact recheck
            rck[row] = ~0ull;
            #pragma unroll
            for (int c = 0; c < 8; ++c)
                if (bm1L[c][tid] <= g1 + GAP_THR) {
                    unsigned int p = atomicAdd(fcount, 1u);
                    flist[p] = row | (c << 17);
                }
        }
    }
    __syncthreads();

    // ---- fused z_st + loss (z tile re-read is L2-hot) ----
    double ls = 0.0;
    const float4* z4  = (const float4*)z;
    const float4* cb4 = (const float4*)cb;
    float4* out4 = (float4*)out;
    #pragma unroll 4
    for (int it = 0; it < 32; ++it) {
        int fi = tid + it * 256;
        int row = fi >> 6, c4 = fi & 63;
        float4 zv = z4[(size_t)(tb * 128 + row) * 64 + c4];
        int idx = gid[row];
        float4 cv = cb4[(size_t)idx * 64 + c4];
        float4 o;
        o.x = zv.x + (cv.x - zv.x);
        o.y = zv.y + (cv.y - zv.y);
        o.z = zv.z + (cv.z - zv.z);
        o.w = zv.w + (cv.w - zv.w);
        out4[(size_t)(tb * 128 + row) * 64 + c4] = o;
        float dx = zv.x - cv.x, dy = zv.y - cv.y, dz = zv.z - cv.z, dw = zv.w - cv.w;
        ls += (double)dx * dx + (double)dy * dy + (double)dz * dz + (double)dw * dw;
    }
    #pragma unroll
    for (int off = 32; off > 0; off >>= 1) ls += __shfl_down(ls, off);
    if (lane == 0) sredD[wid] = ls;
    __syncthreads();
    if (tid == 0) lparts[tb] = (sredD[0] + sredD[1]) + (sredD[2] + sredD[3]);
}

// ---- exact np-f32-chain recheck: ONE WAVE PER (row, block) PAIR, no barriers.
// Each lane owns 2 codes; chains strictly sequential k=0..255 (bit-exact np).
// Wave u64 shfl-min (dq>0 -> f32 bits monotone; low 32 bits = code -> lowest-index ties),
// then one atomicMin into rck[row].
__global__ __launch_bounds__(256)
void vq_recheck_pairs(const float* __restrict__ z, const float* __restrict__ cbT,
                      const float* __restrict__ cnorm, const int* __restrict__ flist,
                      const unsigned int* __restrict__ fcount,
                      unsigned long long* __restrict__ rck)
{
    const int tid  = threadIdx.x;
    const int wid  = tid >> 6;
    const int lane = tid & 63;
    const unsigned int cnt = *fcount;

    for (unsigned int p = blockIdx.x * 4 + wid; p < cnt; p += gridDim.x * 4) {
        const int e   = flist[p];
        const int row = e & 0x1FFFF;
        const int blk = ((unsigned int)e) >> 17;
        const float* zr = z + (size_t)row * DIM;

        // zz: f64 square-sum of this row (coalesced float4 per lane + shfl reduce)
        float4 zv = ((const float4*)zr)[lane];
        double s = 0.0;
        s = fma((double)zv.x, (double)zv.x, s);
        s = fma((double)zv.y, (double)zv.y, s);
        s = fma((double)zv.z, (double)zv.z, s);
        s = fma((double)zv.w, (double)zv.w, s);
        #pragma unroll
        for (int off = 32; off > 0; off >>= 1) s += __shfl_xor(s, off);
        const float zz = (float)s;

        const int c0 = blk * 128 + lane;        // lane's two codes (c0 < c0+64)
        float e0 = 0.0f, e1 = 0.0f;
        #pragma unroll 8
        for (int d4 = 0; d4 < 64; ++d4) {       // strict sequential k = 0..255
            float4 zq = ((const float4*)zr)[d4];            // wave-uniform, L1-hot
            float4 a  = ((const float4*)cbT)[d4 * KC + c0];      // coalesced over lanes
            float4 b  = ((const float4*)cbT)[d4 * KC + c0 + 64];
            e0 = fmaf(zq.x, a.x, e0); e0 = fmaf(zq.y, a.y, e0);
            e0 = fmaf(zq.z, a.z, e0); e0 = fmaf(zq.w, a.w, e0);
            e1 = fmaf(zq.x, b.x, e1); e1 = fmaf(zq.y, b.y, e1);
            e1 = fmaf(zq.z, b.z, e1); e1 = fmaf(zq.w, b.w, e1);
        }
        const float dq0 = fmaf(e0, -2.0f, zz + cnorm[c0]);       // fl(fl(zz+cc) - fl(2e))
        const float dq1 = fmaf(e1, -2.0f, zz + cnorm[c0 + 64]);
        unsigned long long k0 = ((unsigned long long)__float_as_uint(dq0) << 32) | (unsigned int)c0;
        unsigned long long k1 = ((unsigned long long)__float_as_uint(dq1) << 32) | (unsigned int)(c0 + 64);
        unsigned long long k = k0 < k1 ? k0 : k1;
        #pragma unroll
        for (int off = 32; off > 0; off >>= 1) {
            unsigned long long o = __shfl_xor(k, off);
            k = o < k ? o : k;
        }
        if (lane == 0) atomicMin(&rck[row], k);
    }
}

// ---- fixup: one wave per pair (duplicates idempotent): final idx + z_st row rewrite
__global__ __launch_bounds__(256)
void vq_fixup(const float* __restrict__ z, const float* __restrict__ cb,
              const int* __restrict__ flist, const unsigned int* __restrict__ fcount,
              const unsigned long long* __restrict__ rck,
              float* __restrict__ out, float* __restrict__ out_idx)
{
    const int tid  = threadIdx.x;
    const int wid  = tid >> 6;
    const int lane = tid & 63;
    const unsigned int cnt = *fcount;

    for (unsigned int p = blockIdx.x * 4 + wid; p < cnt; p += gridDim.x * 4) {
        const int row  = flist[p] & 0x1FFFF;
        const int code = (int)(unsigned int)rck[row];   // low 32 bits = winning code
        float4 zv = ((const float4*)z)[(size_t)row * 64 + lane];
        float4 cv = ((const float4*)cb)[(size_t)code * 64 + lane];
        float4 o;
        o.x = zv.x + (cv.x - zv.x);
        o.y = zv.y + (cv.y - zv.y);
        o.z = zv.z + (cv.z - zv.z);
        o.w = zv.w + (cv.w - zv.w);
        ((float4*)out)[(size_t)row * 64 + lane] = o;
        if (lane == 0) out_idx[row] = (float)code;
    }
}

__global__ void vq_loss_final(const double* __restrict__ lparts, float* __restrict__ out_loss) {
    __shared__ double s[256];
    const int tid = threadIdx.x;
    double a = 0.0;
    for (int i = tid; i < NBLK; i += 256) a += lparts[i];
    s[tid] = a;
    __syncthreads();
    for (int sft = 128; sft > 0; sft >>= 1) {
        if (tid < sft) s[tid] += s[tid + sft];
        __syncthreads();
    }
    if (tid == 0) {
        float mean = (float)(s[0] / (double)((size_t)N_TOK * DIM));
        out_loss[0] = 0.25f * mean + mean;   // commit + codebook, reference op order
    }
}

extern "C" void kernel_launch(void* const* d_in, const int* in_sizes, int n_in,
                              void* d_out, int out_size, void* d_ws, size_t ws_size,
                              hipStream_t stream) {
    const float* z  = (const float*)d_in[0];
    const float* cb = (const float*)d_in[1];
    float* out = (float*)d_out;
    char* ws = (char*)d_ws;

    unsigned short*     cb16   = (unsigned short*)(ws);
    float*              cnorm  = (float*)(ws + 524288);
    float*              cbT    = (float*)(ws + 528384);
    unsigned int*       fcount = (unsigned int*)(ws + 1576960);
    int*                flist  = (int*)(ws + 1577024);
    unsigned long long* rck    = (unsigned long long*)(ws + 5771328);
    double*             lparts = (double*)(ws + 6819904);

    float* out_idx  = out + (size_t)N_TOK * DIM;
    float* out_loss = out_idx + N_TOK;

    vq_zero<<<1, 64, 0, stream>>>(fcount);
    vq_prep_cb<<<KC / 4, 256, 0, stream>>>(cb, cb16, cnorm);
    vq_transpose<<<(KC * DIM / 4) / 256, 256, 0, stream>>>(cb, cbT);
    vq_scores_fused<<<NBLK, 256, 0, stream>>>(z, cb16, cb, cnorm, out, out_idx,
                                              flist, fcount, rck, lparts);
    vq_recheck_pairs<<<1024, 256, 0, stream>>>(z, cbT, cnorm, flist, fcount, rck);
    vq_fixup<<<512, 256, 0, stream>>>(z, cb, flist, fcount, rck, out, out_idx);
    vq_loss_final<<<1, 256, 0, stream>>>(lparts, out_loss);
}

// Round 10
// 383.384 us; speedup vs baseline: 20.7590x; 1.1287x over previous
//
#include <hip/hip_runtime.h>

#define N_TOK 131072
#define KC    1024
#define DIM   256
#define GAP_THR 4e-4f
#define NBLK  (N_TOK / 128)      // 1024 token blocks

typedef __attribute__((ext_vector_type(8)))  short bf16x8;
typedef __attribute__((ext_vector_type(16))) float f32x16;

__device__ __forceinline__ unsigned short f2bf(float f) {
    unsigned int u = __float_as_uint(f);
    unsigned int r = (u + 0x7fffu + ((u >> 16) & 1u)) >> 16;   // RNE
    return (unsigned short)r;
}

// ================= ws layout =================
// 0       : cb16  (bf16)      524288 B
// 524288  : cnorm (f32)         4096 B
// 528384  : cbT   (f32)      1048576 B   cbT[d4][code][4] transposed codebook
// 1576960 : fcount (u32)          64 B
// 1577024 : flist (int)      4194304 B   entry = row | (blk << 17), one per pair
// 5771328 : rck   (u64)      1048576 B   per-row (dq_bits<<32 | code) atomicMin
// 6819904 : lparts (f64)        8192 B
#define WS_NEED 6828096ull

// cb -> bf16 + f64 norms (one wave per code); block 0 also zeroes fcount
__global__ void vq_prep_cb(const float* __restrict__ cb, unsigned short* __restrict__ cb16,
                           float* __restrict__ cnorm, unsigned int* __restrict__ fcount) {
    if (blockIdx.x == 0 && threadIdx.x == 0) *fcount = 0u;
    int code = blockIdx.x * 4 + (threadIdx.x >> 6);
    int lane = threadIdx.x & 63;
    float4 v = ((const float4*)cb)[(size_t)code * 64 + lane];
    ushort4 h;
    h.x = f2bf(v.x); h.y = f2bf(v.y); h.z = f2bf(v.z); h.w = f2bf(v.w);
    ((ushort4*)cb16)[(size_t)code * 64 + lane] = h;
    double s = 0.0;
    s = fma((double)v.x, (double)v.x, s);
    s = fma((double)v.y, (double)v.y, s);
    s = fma((double)v.z, (double)v.z, s);
    s = fma((double)v.w, (double)v.w, s);
    #pragma unroll
    for (int off = 32; off > 0; off >>= 1) s += __shfl_xor(s, off);
    if (lane == 0) cnorm[code] = (float)s;
}

// cbT[d4][code][4] = cb[code][4*d4 .. 4*d4+4)
__global__ void vq_transpose(const float* __restrict__ cb, float* __restrict__ cbT) {
    int g = blockIdx.x * 256 + threadIdx.x;       // [0, 65536)
    int d4 = g >> 10, code = g & 1023;
    ((float4*)cbT)[g] = ((const float4*)cb)[(size_t)code * 64 + d4];
}

// ---- Fused: bf16 MFMA scores over ALL 1024 codes + per-token argmin/top-2 +
//      pair flagging + z_st output + loss partial. One HBM pass over z per block.
// Block: 4 waves; EACH WAVE = 32 tokens x 128 codes per cbk-tile (token split, not
// code split): B-frags 64 VGPR, acc[4] 64 VGPR -> no spills (R9's 2x2 split spilled).
// Per-wave top-2 state fully register-resident; no inter-wave epilogue merge.
__global__ __launch_bounds__(256, 2)
void vq_scores_fused(const float* __restrict__ z, const unsigned short* __restrict__ cb16,
                     const float* __restrict__ cb, const float* __restrict__ cnorm,
                     float* __restrict__ out, float* __restrict__ out_idx,
                     int* __restrict__ flist, unsigned int* __restrict__ fcount,
                     unsigned long long* __restrict__ rck, double* __restrict__ lparts)
{
    __shared__ uint4  cA[128 * 32];     // 64 KB : 128 codes x 256 dims bf16, 16B-unit swizzled
    __shared__ float  cnsL[KC];         // 4 KB
    __shared__ float  bm1L[8][128];     // 4 KB : per-cbk per-token block-min (LDS, not regs: rule #20)
    __shared__ double sredD[4];

    const int tid  = threadIdx.x;
    const int lane = tid & 63;
    const int l31  = lane & 31;
    const int hi   = lane >> 5;
    const int wid  = tid >> 6;          // wave = token group
    const int tb   = blockIdx.x;
    const int ltok = wid * 32 + l31;    // local token 0..127

    #pragma unroll
    for (int k = 0; k < 4; ++k) cnsL[tid + k * 256] = cnorm[tid + k * 256];

    // ---- B fragments from global f32 (hi-pairs consume 64B line chunks) + f64 zz ----
    bf16x8 bfr[4][4];
    const float* zr = z + (size_t)(tb * 128 + ltok) * DIM;
    double s = 0.0;
    #pragma unroll
    for (int kb = 0; kb < 4; ++kb)
        #pragma unroll
        for (int ks = 0; ks < 4; ++ks) {
            const int d0 = kb * 64 + ks * 16 + hi * 8;
            float4 x = *(const float4*)(zr + d0);
            float4 y = *(const float4*)(zr + d0 + 4);
            s = fma((double)x.x, (double)x.x, s);
            s = fma((double)x.y, (double)x.y, s);
            s = fma((double)x.z, (double)x.z, s);
            s = fma((double)x.w, (double)x.w, s);
            s = fma((double)y.x, (double)y.x, s);
            s = fma((double)y.y, (double)y.y, s);
            s = fma((double)y.z, (double)y.z, s);
            s = fma((double)y.w, (double)y.w, s);
            bf16x8 v;
            v[0] = (short)f2bf(x.x); v[1] = (short)f2bf(x.y);
            v[2] = (short)f2bf(x.z); v[3] = (short)f2bf(x.w);
            v[4] = (short)f2bf(y.x); v[5] = (short)f2bf(y.y);
            v[6] = (short)f2bf(y.z); v[7] = (short)f2bf(y.w);
            bfr[kb][ks] = v;
        }
    s += __shfl_xor(s, 32);             // partner lane holds the other dim-half
    const float zzr = (float)s;         // uniform per-row shift: argmin-invariant

    float gm1 = 3.0e38f, gm2 = 3.0e38f; int gid_ = 0x7fffffff;

    // ---- loop all 8 code blocks ----
    #pragma unroll 1
    for (int cbk = 0; cbk < 8; ++cbk) {
        __syncthreads();                 // previous tile consumed; cnsL visible on iter 0
        #pragma unroll
        for (int i = 0; i < 16; ++i) {   // stage 64 KB code tile, swizzled 16B units
            int g = tid + i * 256;
            int c = g >> 5, u = g & 31;
            cA[c * 32 + (u ^ (c & 7))] = ((const uint4*)cb16)[(size_t)(cbk * 128 + c) * 32 + u];
        }
        __syncthreads();

        f32x16 acc[4];
        #pragma unroll
        for (int a = 0; a < 4; ++a)
            #pragma unroll
            for (int r = 0; r < 16; ++r) acc[a][r] = 0.0f;

        #pragma unroll
        for (int kb = 0; kb < 4; ++kb)
            #pragma unroll
            for (int ks = 0; ks < 4; ++ks) {
                const bf16x8 bv = bfr[kb][ks];
                #pragma unroll
                for (int a = 0; a < 4; ++a) {
                    int c = a * 32 + l31;
                    bf16x8 af = ((const bf16x8*)cA)[c * 32 + ((kb * 8 + ks * 2 + hi) ^ (c & 7))];
                    acc[a] = __builtin_amdgcn_mfma_f32_32x32x16_bf16(af, bv, acc[a], 0, 0, 0);
                }
            }

        // epilogue (register-only): top-2 + lowest-index over 128 codes for this lane's token.
        // C layout (32x32): col=lane&31 (token), row=(r&3)+8*(r>>2)+4*hi (code)
        float c1 = 3.0e38f, c2 = 3.0e38f;
        #pragma unroll
        for (int a = 0; a < 4; ++a)
            #pragma unroll
            for (int r = 0; r < 16; ++r) {
                int cl = a * 32 + (r & 3) + 8 * (r >> 2) + 4 * hi;
                float A  = zzr + cnsL[cbk * 128 + cl];     // fl(zz+cc), broadcast read
                float dq = fmaf(acc[a][r], -2.0f, A);      // fl(A - fl(2e)), 2e exact
                acc[a][r] = dq;
                float hv = fmaxf(c1, dq);
                c1 = fminf(c1, dq);
                c2 = fminf(c2, hv);                        // dup minima -> gap 0 -> flagged
            }
        int ci = 0x7fffffff;
        #pragma unroll
        for (int a = 0; a < 4; ++a)
            #pragma unroll
            for (int r = 0; r < 16; ++r) {
                int code = cbk * 128 + a * 32 + (r & 3) + 8 * (r >> 2) + 4 * hi;
                ci = min(ci, (acc[a][r] == c1) ? code : 0x7fffffff);
            }
        // merge lane <-> lane^32 (same token, other code rows)
        float o1 = __shfl_xor(c1, 32);
        float o2 = __shfl_xor(c2, 32);
        int  oi  = __shfl_xor(ci, 32);
        float nm2 = fminf(fminf(c2, o2), fmaxf(c1, o1));
        int  ni  = (o1 < c1 || (o1 == c1 && oi < ci)) ? oi : ci;
        float nm1 = fminf(c1, o1);
        if (hi == 0) bm1L[cbk][ltok] = nm1;
        // update running state (registers)
        float ng2 = fminf(fminf(gm2, nm2), fmaxf(gm1, nm1));
        if (nm1 < gm1 || (nm1 == gm1 && ni < gid_)) { gm1 = nm1; gid_ = ni; }
        gm2 = ng2;
    }

    // ---- flag pairs + provisional index (hi==0 lane owns its token; reads own bm1L writes) ----
    const int rowg = tb * 128 + ltok;
    if (hi == 0) {
        out_idx[rowg] = (float)gid_;
        float gap = gm2 - gm1;
        if (!(gap > GAP_THR)) {           // near-tie or NaN safety -> exact recheck
            rck[rowg] = ~0ull;
            #pragma unroll
            for (int c = 0; c < 8; ++c)
                if (bm1L[c][ltok] <= gm1 + GAP_THR) {
                    unsigned int p = atomicAdd(fcount, 1u);
                    flist[p] = rowg | (c << 17);
                }
        }
    }

    // ---- fused z_st + loss: wave writes its own 32 rows (z re-read L2/L3-hot) ----
    double ls = 0.0;
    #pragma unroll 4
    for (int r = 0; r < 32; ++r) {
        int idx = __shfl(gid_, r);                       // wave-uniform per row
        size_t row = (size_t)tb * 128 + wid * 32 + r;
        float4 zv = ((const float4*)z)[row * 64 + lane];
        float4 cv = ((const float4*)cb)[(size_t)idx * 64 + lane];
        float4 o;
        o.x = zv.x + (cv.x - zv.x);
        o.y = zv.y + (cv.y - zv.y);
        o.z = zv.z + (cv.z - zv.z);
        o.w = zv.w + (cv.w - zv.w);
        ((float4*)out)[row * 64 + lane] = o;
        float dx = zv.x - cv.x, dy = zv.y - cv.y, dz = zv.z - cv.z, dw = zv.w - cv.w;
        ls += (double)dx * dx + (double)dy * dy + (double)dz * dz + (double)dw * dw;
    }
    #pragma unroll
    for (int off = 32; off > 0; off >>= 1) ls += __shfl_down(ls, off);
    if (lane == 0) sredD[wid] = ls;
    __syncthreads();
    if (tid == 0) lparts[tb] = (sredD[0] + sredD[1]) + (sredD[2] + sredD[3]);
}

// ---- exact np-f32-chain recheck: ONE WAVE PER (row, block) PAIR, no barriers. ----
__global__ __launch_bounds__(256)
void vq_recheck_pairs(const float* __restrict__ z, const float* __restrict__ cbT,
                      const float* __restrict__ cnorm, const int* __restrict__ flist,
                      const unsigned int* __restrict__ fcount,
                      unsigned long long* __restrict__ rck)
{
    const int tid  = threadIdx.x;
    const int wid  = tid >> 6;
    const int lane = tid & 63;
    const unsigned int cnt = *fcount;

    for (unsigned int p = blockIdx.x * 4 + wid; p < cnt; p += gridDim.x * 4) {
        const int e   = flist[p];
        const int row = e & 0x1FFFF;
        const int blk = ((unsigned int)e) >> 17;
        const float* zr = z + (size_t)row * DIM;

        float4 zv = ((const float4*)zr)[lane];
        double s = 0.0;
        s = fma((double)zv.x, (double)zv.x, s);
        s = fma((double)zv.y, (double)zv.y, s);
        s = fma((double)zv.z, (double)zv.z, s);
        s = fma((double)zv.w, (double)zv.w, s);
        #pragma unroll
        for (int off = 32; off > 0; off >>= 1) s += __shfl_xor(s, off);
        const float zz = (float)s;

        const int c0 = blk * 128 + lane;        // lane's two codes (c0 < c0+64)
        float e0 = 0.0f, e1 = 0.0f;
        #pragma unroll 8
        for (int d4 = 0; d4 < 64; ++d4) {       // strict sequential k = 0..255
            float4 zq = ((const float4*)zr)[d4];             // wave-uniform, L1-hot
            float4 a  = ((const float4*)cbT)[d4 * KC + c0];  // coalesced over lanes
            float4 b  = ((const float4*)cbT)[d4 * KC + c0 + 64];
            e0 = fmaf(zq.x, a.x, e0); e0 = fmaf(zq.y, a.y, e0);
            e0 = fmaf(zq.z, a.z, e0); e0 = fmaf(zq.w, a.w, e0);
            e1 = fmaf(zq.x, b.x, e1); e1 = fmaf(zq.y, b.y, e1);
            e1 = fmaf(zq.z, b.z, e1); e1 = fmaf(zq.w, b.w, e1);
        }
        const float dq0 = fmaf(e0, -2.0f, zz + cnorm[c0]);       // fl(fl(zz+cc) - fl(2e))
        const float dq1 = fmaf(e1, -2.0f, zz + cnorm[c0 + 64]);
        unsigned long long k0 = ((unsigned long long)__float_as_uint(dq0) << 32) | (unsigned int)c0;
        unsigned long long k1 = ((unsigned long long)__float_as_uint(dq1) << 32) | (unsigned int)(c0 + 64);
        unsigned long long k = k0 < k1 ? k0 : k1;
        #pragma unroll
        for (int off = 32; off > 0; off >>= 1) {
            unsigned long long o = __shfl_xor(k, off);
            k = o < k ? o : k;
        }
        if (lane == 0) atomicMin(&rck[row], k);
    }
}

// ---- fixup: one wave per pair (duplicates idempotent): final idx + z_st row rewrite
__global__ __launch_bounds__(256)
void vq_fixup(const float* __restrict__ z, const float* __restrict__ cb,
              const int* __restrict__ flist, const unsigned int* __restrict__ fcount,
              const unsigned long long* __restrict__ rck,
              float* __restrict__ out, float* __restrict__ out_idx)
{
    const int tid  = threadIdx.x;
    const int wid  = tid >> 6;
    const int lane = tid & 63;
    const unsigned int cnt = *fcount;

    for (unsigned int p = blockIdx.x * 4 + wid; p < cnt; p += gridDim.x * 4) {
        const int row  = flist[p] & 0x1FFFF;
        const int code = (int)(unsigned int)rck[row];   // low 32 bits = winning code
        float4 zv = ((const float4*)z)[(size_t)row * 64 + lane];
        float4 cv = ((const float4*)cb)[(size_t)code * 64 + lane];
        float4 o;
        o.x = zv.x + (cv.x - zv.x);
        o.y = zv.y + (cv.y - zv.y);
        o.z = zv.z + (cv.z - zv.z);
        o.w = zv.w + (cv.w - zv.w);
        ((float4*)out)[(size_t)row * 64 + lane] = o;
        if (lane == 0) out_idx[row] = (float)code;
    }
}

__global__ void vq_loss_final(const double* __restrict__ lparts, float* __restrict__ out_loss) {
    __shared__ double s[256];
    const int tid = threadIdx.x;
    double a = 0.0;
    for (int i = tid; i < NBLK; i += 256) a += lparts[i];
    s[tid] = a;
    __syncthreads();
    for (int sft = 128; sft > 0; sft >>= 1) {
        if (tid < sft) s[tid] += s[tid + sft];
        __syncthreads();
    }
    if (tid == 0) {
        float mean = (float)(s[0] / (double)((size_t)N_TOK * DIM));
        out_loss[0] = 0.25f * mean + mean;   // commit + codebook, reference op order
    }
}

extern "C" void kernel_launch(void* const* d_in, const int* in_sizes, int n_in,
                              void* d_out, int out_size, void* d_ws, size_t ws_size,
                              hipStream_t stream) {
    const float* z  = (const float*)d_in[0];
    const float* cb = (const float*)d_in[1];
    float* out = (float*)d_out;
    char* ws = (char*)d_ws;

    unsigned short*     cb16   = (unsigned short*)(ws);
    float*              cnorm  = (float*)(ws + 524288);
    float*              cbT    = (float*)(ws + 528384);
    unsigned int*       fcount = (unsigned int*)(ws + 1576960);
    int*                flist  = (int*)(ws + 1577024);
    unsigned long long* rck    = (unsigned long long*)(ws + 5771328);
    double*             lparts = (double*)(ws + 6819904);

    float* out_idx  = out + (size_t)N_TOK * DIM;
    float* out_loss = out_idx + N_TOK;

    vq_prep_cb<<<KC / 4, 256, 0, stream>>>(cb, cb16, cnorm, fcount);
    vq_transpose<<<(KC * DIM / 4) / 256, 256, 0, stream>>>(cb, cbT);
    vq_scores_fused<<<NBLK, 256, 0, stream>>>(z, cb16, cb, cnorm, out, out_idx,
                                              flist, fcount, rck, lparts);
    vq_recheck_pairs<<<1024, 256, 0, stream>>>(z, cbT, cnorm, flist, fcount, rck);
    vq_fixup<<<512, 256, 0, stream>>>(z, cb, flist, fcount, rck, out, out_idx);
    vq_loss_final<<<1, 256, 0, stream>>>(lparts, out_loss);
}